// Round 4
// baseline (3540.860 us; speedup 1.0000x reference)
//
#include <hip/hip_runtime.h>
#include <math.h>

#define NVOX 60000

typedef __attribute__((ext_vector_type(8))) short short8v;            // 8 bf16 raw
typedef __attribute__((ext_vector_type(8))) unsigned short ushort8v;  // 8 bf16 raw
typedef __attribute__((ext_vector_type(4))) float f32x4;

static __device__ __forceinline__ unsigned short f2bf(float f) {
    unsigned u = __float_as_uint(f);
    unsigned r = (u + 0x7fffu + ((u >> 16) & 1u)) >> 16;
    return (unsigned short)r;
}
static __device__ __forceinline__ float bf2f(unsigned short h) {
    return __uint_as_float(((unsigned)h) << 16);
}
// async global->LDS 16B per lane: dest = lds_base + lane*16 (wave-uniform base)
static __device__ __forceinline__ void gll16(const unsigned short* g, unsigned short* l) {
    __builtin_amdgcn_global_load_lds(
        (const __attribute__((address_space(1))) unsigned*)g,
        (__attribute__((address_space(3))) unsigned*)l,
        16, 0, 0);
}

// ---------------------------------------------------------------- pos embed (bf16 out)
__global__ __launch_bounds__(256) void pos_kernel(const float* __restrict__ ciw,
                                                  unsigned short* __restrict__ pos) {
    int idx = blockIdx.x * 256 + threadIdx.x;
    if (idx >= NVOX * 128) return;
    int n = idx >> 7, d = idx & 127;
    int c = d >> 6, t = (d & 63) >> 1;
    float xy = ciw[n * 2 + c] - 6.0f;
    float inv = exp2f((float)t * (13.287712379549449f / 32.0f)); // 10000^(t/32)
    float e = xy / inv;
    pos[idx] = f2bf((d & 1) ? cosf(e) : sinf(e));
}

// ------------------------------------------------------- fp32 -> bf16 convert
__global__ __launch_bounds__(256) void cvt_bf16(const float* __restrict__ in,
                                                unsigned short* __restrict__ out, int n) {
    int idx = blockIdx.x * 256 + threadIdx.x;
    if (idx < n) out[idx] = f2bf(in[idx]);
}

// -------------------------------------------- feat init: f32 copy + bf16 shadow
__global__ __launch_bounds__(256) void feat_init(const float* __restrict__ vf,
                                                 float* __restrict__ feat,
                                                 unsigned short* __restrict__ featb) {
    int idx = blockIdx.x * 256 + threadIdx.x;
    if (idx >= NVOX * 128) return;
    float v = vf[idx];
    feat[idx] = v;
    featb[idx] = f2bf(v);
}

// ----------------------------------------- MFMA GEMM: C = A*W^T + b (+variants)
// A bf16 [M,KTOT]; W bf16 [N,KTOT]; optional A+=Aadd (bf16, K=128) for
// col-blocks < add_nblk; C f32/bf16 (+GELU); LNF: fused residual+LN epilogue
// (N==128, gridDim.y==1): feat = LN(feat + A@W^T + b)*g + b2, also writes featb.
template<int KTOT, bool ADD, bool GELU, bool CBF16, bool LNF>
__global__ __launch_bounds__(256) void gemm_mfma(
    const unsigned short* __restrict__ A, const unsigned short* __restrict__ Aadd, int add_nblk,
    const unsigned short* __restrict__ W, const float* __restrict__ bias,
    void* __restrict__ Cp, int M, int ldc,
    float* __restrict__ feat, unsigned short* __restrict__ featb,
    const float* __restrict__ lng, const float* __restrict__ lnb)
{
    __shared__ unsigned short As[128 * 64];
    __shared__ unsigned short Ws[128 * 64];
    __shared__ float2 lnsum[128][2];
    const int tid = threadIdx.x;
    const int lane = tid & 63, wave = tid >> 6;
    const int wr = wave >> 1, wc = wave & 1;
    const int llo = lane & 15, lhi = lane >> 4;
    const int m0 = blockIdx.x * 128;
    const int n0 = blockIdx.y * 128;
    const bool addp = ADD && ((int)blockIdx.y < add_nblk);
    const int gr = lane >> 3;           // row within 8-row group
    const int gc = (lane & 7) ^ gr;     // pre-swizzled source chunk
    f32x4 acc[4][4] = {};

    for (int k0 = 0; k0 < KTOT; k0 += 64) {
        // ---- stage W via async global->LDS (source pre-swizzled, dest linear)
        #pragma unroll
        for (int p = 0; p < 4; ++p) {
            int r0 = wave * 32 + p * 8;
            gll16(W + (size_t)(n0 + r0 + gr) * KTOT + k0 + gc * 8, &Ws[r0 * 64]);
        }
        if (!addp) {
            #pragma unroll
            for (int p = 0; p < 4; ++p) {
                int r0 = wave * 32 + p * 8;
                gll16(A + (size_t)(m0 + r0 + gr) * KTOT + k0 + gc * 8, &As[r0 * 64]);
            }
        } else {
            #pragma unroll
            for (int p = 0; p < 4; ++p) {
                int c = tid + p * 256;
                int r = c >> 3, c16 = c & 7;
                int m = m0 + r;
                short8v av = {};
                if (m < M) {
                    ushort8v fa = *reinterpret_cast<const ushort8v*>(A + (size_t)m * KTOT + k0 + c16 * 8);
                    ushort8v pa = *reinterpret_cast<const ushort8v*>(Aadd + (size_t)m * 128 + k0 + c16 * 8);
                    #pragma unroll
                    for (int q = 0; q < 8; ++q) av[q] = (short)f2bf(bf2f(fa[q]) + bf2f(pa[q]));
                }
                *reinterpret_cast<short8v*>((char*)As + r * 128 + ((c16 * 16) ^ ((r & 7) << 4))) = av;
            }
        }
        __syncthreads();
        #pragma unroll
        for (int kk = 0; kk < 2; ++kk) {
            int kb = kk * 64 + lhi * 16;
            short8v af[4], bf[4];
            #pragma unroll
            for (int i = 0; i < 4; ++i) {
                int r = wr * 64 + i * 16 + llo;
                af[i] = *reinterpret_cast<const short8v*>((const char*)As + r * 128 + (kb ^ ((r & 7) << 4)));
                int cc = wc * 64 + i * 16 + llo;
                bf[i] = *reinterpret_cast<const short8v*>((const char*)Ws + cc * 128 + (kb ^ ((cc & 7) << 4)));
            }
            #pragma unroll
            for (int i = 0; i < 4; ++i)
                #pragma unroll
                for (int j = 0; j < 4; ++j)
                    acc[i][j] = __builtin_amdgcn_mfma_f32_16x16x32_bf16(af[i], bf[j], acc[i][j], 0, 0, 0);
        }
        __syncthreads();
    }

    if (LNF) {
        float s1[4][4] = {}, s2[4][4] = {};
        #pragma unroll
        for (int i = 0; i < 4; ++i)
            #pragma unroll
            for (int rg = 0; rg < 4; ++rg) {
                int m = m0 + wr * 64 + i * 16 + lhi * 4 + rg;
                if (m < M) {
                    #pragma unroll
                    for (int j = 0; j < 4; ++j) {
                        int n = wc * 64 + j * 16 + llo;
                        float x = feat[(size_t)m * 128 + n] + acc[i][j][rg] + bias[n];
                        s1[i][rg] += x; s2[i][rg] += x * x;
                    }
                }
            }
        #pragma unroll
        for (int i = 0; i < 4; ++i)
            #pragma unroll
            for (int rg = 0; rg < 4; ++rg) {
                #pragma unroll
                for (int off = 1; off < 16; off <<= 1) {
                    s1[i][rg] += __shfl_xor(s1[i][rg], off);
                    s2[i][rg] += __shfl_xor(s2[i][rg], off);
                }
                if (llo == 0)
                    lnsum[wr * 64 + i * 16 + lhi * 4 + rg][wc] = make_float2(s1[i][rg], s2[i][rg]);
            }
        __syncthreads();
        #pragma unroll
        for (int i = 0; i < 4; ++i)
            #pragma unroll
            for (int rg = 0; rg < 4; ++rg) {
                int r = wr * 64 + i * 16 + lhi * 4 + rg;
                int m = m0 + r;
                if (m >= M) continue;
                float2 a0 = lnsum[r][0], a1 = lnsum[r][1];
                float mu = (a0.x + a1.x) * 0.0078125f;
                float var = fmaxf((a0.y + a1.y) * 0.0078125f - mu * mu, 0.f);
                float inv = rsqrtf(var + 1e-5f);
                #pragma unroll
                for (int j = 0; j < 4; ++j) {
                    int n = wc * 64 + j * 16 + llo;
                    float x = feat[(size_t)m * 128 + n] + acc[i][j][rg] + bias[n];
                    float v = (x - mu) * inv * lng[n] + lnb[n];
                    feat[(size_t)m * 128 + n] = v;
                    featb[(size_t)m * 128 + n] = f2bf(v);
                }
            }
    } else {
        #pragma unroll
        for (int j = 0; j < 4; ++j) {
            int n = n0 + wc * 64 + j * 16 + llo;
            float bn = bias[n];
            #pragma unroll
            for (int i = 0; i < 4; ++i) {
                #pragma unroll
                for (int rg = 0; rg < 4; ++rg) {
                    int m = m0 + wr * 64 + i * 16 + lhi * 4 + rg;
                    if (m < M) {
                        float v = acc[i][j][rg] + bn;
                        if (GELU) v = 0.5f * v * (1.0f + erff(v * 0.7071067811865475f));
                        if (CBF16) ((unsigned short*)Cp)[(size_t)m * ldc + n] = f2bf(v);
                        else       ((float*)Cp)[(size_t)m * ldc + n] = v;
                    }
                }
            }
        }
    }
}

// ------------------------------------------------------- windowed attention (bf16 qkv)
template<int CAPT, int HG>
__global__ __launch_bounds__(256) void attn_kernel(
    const unsigned short* __restrict__ qkv, const int* __restrict__ vlist, int nvox,
    unsigned short* __restrict__ oout)
{
    __shared__ float Ks[CAPT][HG * 16];
    __shared__ float Vs[CAPT][HG * 16];
    __shared__ int vl[CAPT];
    const int w = blockIdx.x;
    const int hb = blockIdx.y * HG;
    const int tid = threadIdx.x;
    const int T = min(CAPT, nvox - w * CAPT);
    if (tid < T) vl[tid] = vlist[w * CAPT + tid];
    constexpr int R8 = HG * 2;
    for (int idx = tid; idx < T * R8; idx += 256) {
        int t = idx / R8, c8 = (idx % R8) * 8;
        int vox = vlist[w * CAPT + t];
        const unsigned short* base = qkv + (size_t)vox * 384 + hb * 16 + c8;
        ushort8v kv = *reinterpret_cast<const ushort8v*>(base + 128);
        ushort8v vv = *reinterpret_cast<const ushort8v*>(base + 256);
        #pragma unroll
        for (int q = 0; q < 8; ++q) { Ks[t][c8 + q] = bf2f(kv[q]); Vs[t][c8 + q] = bf2f(vv[q]); }
    }
    __syncthreads();
    const int ITEMS = T * HG;
    for (int item = tid; item < ITEMS; item += 256) {
        int h = item & (HG - 1);
        int q = item / HG;
        int vq = vl[q];
        const unsigned short* qb = qkv + (size_t)vq * 384 + (hb + h) * 16;
        ushort8v qa = *reinterpret_cast<const ushort8v*>(qb);
        ushort8v qc = *reinterpret_cast<const ushort8v*>(qb + 8);
        float4 q0 = make_float4(bf2f(qa[0]), bf2f(qa[1]), bf2f(qa[2]), bf2f(qa[3]));
        float4 q1 = make_float4(bf2f(qa[4]), bf2f(qa[5]), bf2f(qa[6]), bf2f(qa[7]));
        float4 q2 = make_float4(bf2f(qc[0]), bf2f(qc[1]), bf2f(qc[2]), bf2f(qc[3]));
        float4 q3 = make_float4(bf2f(qc[4]), bf2f(qc[5]), bf2f(qc[6]), bf2f(qc[7]));
        float mx = -INFINITY, l = 0.f;
        float4 o0 = make_float4(0,0,0,0), o1 = o0, o2 = o0, o3 = o0;
        for (int t = 0; t < T; ++t) {
            const float4* kr = reinterpret_cast<const float4*>(&Ks[t][h * 16]);
            float4 k0 = kr[0], k1 = kr[1], k2 = kr[2], k3 = kr[3];
            float s = q0.x*k0.x + q0.y*k0.y + q0.z*k0.z + q0.w*k0.w
                    + q1.x*k1.x + q1.y*k1.y + q1.z*k1.z + q1.w*k1.w
                    + q2.x*k2.x + q2.y*k2.y + q2.z*k2.z + q2.w*k2.w
                    + q3.x*k3.x + q3.y*k3.y + q3.z*k3.z + q3.w*k3.w;
            s *= 0.25f;
            float mo = mx;
            mx = fmaxf(mx, s);
            float cc = __expf(mo - mx);
            float p  = __expf(s - mx);
            l = l * cc + p;
            const float4* vr = reinterpret_cast<const float4*>(&Vs[t][h * 16]);
            float4 v0 = vr[0], v1 = vr[1], v2 = vr[2], v3 = vr[3];
            o0.x = o0.x*cc + p*v0.x; o0.y = o0.y*cc + p*v0.y; o0.z = o0.z*cc + p*v0.z; o0.w = o0.w*cc + p*v0.w;
            o1.x = o1.x*cc + p*v1.x; o1.y = o1.y*cc + p*v1.y; o1.z = o1.z*cc + p*v1.z; o1.w = o1.w*cc + p*v1.w;
            o2.x = o2.x*cc + p*v2.x; o2.y = o2.y*cc + p*v2.y; o2.z = o2.z*cc + p*v2.z; o2.w = o2.w*cc + p*v2.w;
            o3.x = o3.x*cc + p*v3.x; o3.y = o3.y*cc + p*v3.y; o3.z = o3.z*cc + p*v3.z; o3.w = o3.w*cc + p*v3.w;
        }
        float rl = 1.0f / l;
        ushort8v r0, r1;
        r0[0]=f2bf(o0.x*rl); r0[1]=f2bf(o0.y*rl); r0[2]=f2bf(o0.z*rl); r0[3]=f2bf(o0.w*rl);
        r0[4]=f2bf(o1.x*rl); r0[5]=f2bf(o1.y*rl); r0[6]=f2bf(o1.z*rl); r0[7]=f2bf(o1.w*rl);
        r1[0]=f2bf(o2.x*rl); r1[1]=f2bf(o2.y*rl); r1[2]=f2bf(o2.z*rl); r1[3]=f2bf(o2.w*rl);
        r1[4]=f2bf(o3.x*rl); r1[5]=f2bf(o3.y*rl); r1[6]=f2bf(o3.z*rl); r1[7]=f2bf(o3.w*rl);
        unsigned short* op = oout + (size_t)vq * 128 + (hb + h) * 16;
        *reinterpret_cast<ushort8v*>(op) = r0;
        *reinterpret_cast<ushort8v*>(op + 8) = r1;
    }
}

// ---------------------------------------- BEV scatter into padded canvas (bf16)
__global__ __launch_bounds__(256) void scatter_kernel(const float* __restrict__ feat,
    const int* __restrict__ coors, unsigned short* __restrict__ canvas)
{
    int idx = blockIdx.x * 256 + threadIdx.x;
    if (idx >= NVOX * 16) return;
    int n = idx >> 4, c8 = (idx & 15) << 3;
    int b = coors[n * 4], y = coors[n * 4 + 2], x = coors[n * 4 + 3];
    const float* src = feat + (size_t)n * 128 + c8;
    float4 u0 = *reinterpret_cast<const float4*>(src);
    float4 u1 = *reinterpret_cast<const float4*>(src + 4);
    ushort8v v;
    v[0]=f2bf(u0.x); v[1]=f2bf(u0.y); v[2]=f2bf(u0.z); v[3]=f2bf(u0.w);
    v[4]=f2bf(u1.x); v[5]=f2bf(u1.y); v[6]=f2bf(u1.z); v[7]=f2bf(u1.w);
    size_t p = (((size_t)b * 404 + y + 2) * 404 + x + 2) * 128 + c8;
    *reinterpret_cast<ushort8v*>(canvas + p) = v;
}

// ------------------- conv weight re-layout -> bf16 [i][ky*3+kx][cout][cin]
__global__ __launch_bounds__(256) void wtrans_kernel(const float* __restrict__ cw,
                                                     unsigned short* __restrict__ wbuf)
{
    int idx = blockIdx.x * 256 + threadIdx.x;
    if (idx >= 2 * 9 * 128 * 128) return;
    int ci = idx & 127;
    int co = (idx >> 7) & 127;
    int kk = (idx >> 14) % 9;
    int i  = idx / (9 * 16384);
    wbuf[idx] = f2bf(cw[(((size_t)i * 128 + co) * 128 + ci) * 9 + kk]);
}

// ---------------- 3x3 dilated(2) conv + BN + ReLU, direct-global MFMA
// in: padded NHWC bf16 [2][404][404][128] (zero halo -> no bounds checks).
// Block: 64px x 128co x 4y, 512 thr = 8 waves (2px x 2co x 2y), no LDS.
template<bool NCHW_OUT>
__global__ __launch_bounds__(512) void conv_mfma(
    const unsigned short* __restrict__ in, const unsigned short* __restrict__ wbuf,
    const float* __restrict__ g, const float* __restrict__ bsh,
    const float* __restrict__ bm, const float* __restrict__ bv,
    void* __restrict__ out)
{
    const int tid = threadIdx.x;
    const int lane = tid & 63, wave = tid >> 6;
    const int pxg = wave & 1, cog = (wave >> 1) & 1, yg = wave >> 2;
    const int llo = lane & 15, lhi = lane >> 4;
    const int x0 = blockIdx.x * 64, y0 = blockIdx.y * 4, b = blockIdx.z;
    const size_t rowstride = 404 * 128;

    f32x4 acc[2][2][4] = {};    // [dy][i(px)][j(co)]
    #pragma unroll
    for (int ky = 0; ky < 3; ++ky) {
        #pragma unroll
        for (int kx = 0; kx < 3; ++kx) {
            const unsigned short* wt = wbuf + (size_t)(ky * 3 + kx) * 16384 + cog * 8192;
            const unsigned short* ab = in + ((size_t)b * 404 + y0 + yg * 2 + 2 * ky) * rowstride
                                          + (size_t)(x0 + pxg * 32 + llo + 2 * kx) * 128;
            #pragma unroll
            for (int kk = 0; kk < 4; ++kk) {
                short8v bfr[4];
                #pragma unroll
                for (int j = 0; j < 4; ++j)
                    bfr[j] = *reinterpret_cast<const short8v*>(wt + (j * 16 + llo) * 128 + kk * 32 + lhi * 8);
                short8v a[2][2];
                #pragma unroll
                for (int dy = 0; dy < 2; ++dy)
                    #pragma unroll
                    for (int i = 0; i < 2; ++i)
                        a[dy][i] = *reinterpret_cast<const short8v*>(
                            ab + (size_t)dy * rowstride + i * (16 * 128) + kk * 32 + lhi * 8);
                #pragma unroll
                for (int dy = 0; dy < 2; ++dy)
                    #pragma unroll
                    for (int i = 0; i < 2; ++i)
                        #pragma unroll
                        for (int j = 0; j < 4; ++j)
                            acc[dy][i][j] = __builtin_amdgcn_mfma_f32_16x16x32_bf16(
                                a[dy][i], bfr[j], acc[dy][i][j], 0, 0, 0);
            }
        }
    }
    #pragma unroll
    for (int j = 0; j < 4; ++j) {
        int co = cog * 64 + j * 16 + llo;
        float scale = rsqrtf(bv[co] + 1e-3f) * g[co];
        float shift = bsh[co] - bm[co] * scale;
        #pragma unroll
        for (int dy = 0; dy < 2; ++dy) {
            int y = y0 + yg * 2 + dy;
            #pragma unroll
            for (int i = 0; i < 2; ++i) {
                #pragma unroll
                for (int rg = 0; rg < 4; ++rg) {
                    int px = x0 + pxg * 32 + i * 16 + lhi * 4 + rg;
                    if (px < 400) {
                        float v = fmaxf(acc[dy][i][j][rg] * scale + shift, 0.f);
                        if (NCHW_OUT)
                            ((float*)out)[(((size_t)b * 128 + co) * 400 + y) * 400 + px] = v;
                        else
                            ((unsigned short*)out)[(((size_t)b * 404 + y + 2) * 404 + px + 2) * 128 + co] = f2bf(v);
                    }
                }
            }
        }
    }
}

// ---------------------------------------------------------------- launcher
extern "C" void kernel_launch(void* const* d_in, const int* in_sizes, int n_in,
                              void* d_out, int out_size, void* d_ws, size_t ws_size,
                              hipStream_t stream) {
    const float* voxel_feat = (const float*)d_in[0];
    const int*   coors      = (const int*)d_in[1];
    const float* ciw0       = (const float*)d_in[2];
    const float* ciw1       = (const float*)d_in[3];
    const int* vx[2][2] = {{(const int*)d_in[4], (const int*)d_in[6]},
                           {(const int*)d_in[8], (const int*)d_in[10]}};
    const float* ipw = (const float*)d_in[12];
    const float* ipb = (const float*)d_in[13];
    const float* ow  = (const float*)d_in[14];
    const float* obp = (const float*)d_in[15];
    const float* l1w = (const float*)d_in[16];
    const float* l1b = (const float*)d_in[17];
    const float* l2w = (const float*)d_in[18];
    const float* l2b = (const float*)d_in[19];
    const float* g1  = (const float*)d_in[20];
    const float* b1  = (const float*)d_in[21];
    const float* g2  = (const float*)d_in[22];
    const float* b2  = (const float*)d_in[23];
    const float* cw  = (const float*)d_in[24];
    const float* bng = (const float*)d_in[25];
    const float* bnb = (const float*)d_in[26];
    const float* bnm = (const float*)d_in[27];
    const float* bnv = (const float*)d_in[28];

    float* F = (float*)d_ws;
    unsigned short* W0   = (unsigned short*)F;           // bf16 weights: 1,867,776
    unsigned short* ipwb = W0;                           // 589824
    unsigned short* owb  = W0 + 589824;                  // 196608
    unsigned short* l1wb = W0 + 786432;                  // 393216
    unsigned short* l2wb = W0 + 1179648;                 // 393216
    unsigned short* cwb  = W0 + 1572864;                 // 294912
    float* feat = F + 940000;                            // 7.68M f32
    unsigned short* featb = (unsigned short*)(F + 8620000);   // 7.68M bf16
    unsigned short* pos0  = (unsigned short*)(F + 12460000);  // 7.68M bf16
    unsigned short* pos1  = (unsigned short*)(F + 16300000);
    unsigned short* obufb = (unsigned short*)(F + 20140000);
    unsigned short* hbufb = (unsigned short*)(F + 23980000);  // 15.36M bf16
    // conv phase (pos/obuf/hbuf dead; feat still live for scatter):
    unsigned short* canvas1 = (unsigned short*)(F + 12460000);  // padded 41.78M bf16
    unsigned short* canvas2 = (unsigned short*)(F + 33360000);  // padded 41.78M bf16
    unsigned short* qkvb = (unsigned short*)d_out;       // 23.04M bf16 scratch

    feat_init<<<30000, 256, 0, stream>>>(voxel_feat, feat, featb);
    pos_kernel<<<30000, 256, 0, stream>>>(ciw0, pos0);
    pos_kernel<<<30000, 256, 0, stream>>>(ciw1, pos1);
    cvt_bf16<<<(589824 + 255) / 256, 256, 0, stream>>>(ipw, ipwb, 589824);
    cvt_bf16<<<(196608 + 255) / 256, 256, 0, stream>>>(ow,  owb,  196608);
    cvt_bf16<<<(393216 + 255) / 256, 256, 0, stream>>>(l1w, l1wb, 393216);
    cvt_bf16<<<(393216 + 255) / 256, 256, 0, stream>>>(l2w, l2wb, 393216);
    wtrans_kernel<<<(2 * 9 * 16384 + 255) / 256, 256, 0, stream>>>(cw, cwb);

    for (int li = 0; li < 12; ++li) {
        int s = li & 1;
        const unsigned short* pos = s ? pos1 : pos0;
        // QKV: q,k col-blocks get +pos (reg-staged); v block pure gll
        gemm_mfma<128, true, false, true, false><<<dim3(469, 3), 256, 0, stream>>>(
            featb, pos, 2, ipwb + (size_t)li * 49152, ipb + li * 384, qkvb, NVOX, 384,
            nullptr, nullptr, nullptr, nullptr);
        attn_kernel<25, 8><<<dim3(960, 1), 256, 0, stream>>>(qkvb, vx[s][0], 24000, obufb);
        attn_kernel<100, 4><<<dim3(360, 2), 256, 0, stream>>>(qkvb, vx[s][1], 36000, obufb);
        // out-proj + residual + LN1 fused
        gemm_mfma<128, false, false, false, true><<<dim3(469, 1), 256, 0, stream>>>(
            obufb, nullptr, 0, owb + (size_t)li * 16384, obp + li * 128, nullptr, NVOX, 128,
            feat, featb, g1 + li * 128, b1 + li * 128);
        // FFN1 + GELU, bf16 out
        gemm_mfma<128, false, true, true, false><<<dim3(469, 2), 256, 0, stream>>>(
            featb, nullptr, 0, l1wb + (size_t)li * 32768, l1b + li * 256, hbufb, NVOX, 256,
            nullptr, nullptr, nullptr, nullptr);
        // FFN2 + residual + LN2 fused
        gemm_mfma<256, false, false, false, true><<<dim3(469, 1), 256, 0, stream>>>(
            hbufb, nullptr, 0, l2wb + (size_t)li * 32768, l2b + li * 128, nullptr, NVOX, 128,
            feat, featb, g2 + li * 128, b2 + li * 128);
    }

    // BEV: zero padded canvases, scatter, conv1 (bf16 padded NHWC), conv2 (fp32 NCHW)
    hipMemsetAsync(canvas1, 0, (size_t)41783296 * 2, stream);
    hipMemsetAsync(canvas2, 0, (size_t)41783296 * 2, stream);
    scatter_kernel<<<(NVOX * 16 + 255) / 256, 256, 0, stream>>>(feat, coors, canvas1);
    conv_mfma<false><<<dim3(7, 100, 2), 512, 0, stream>>>(
        canvas1, cwb, bng, bnb, bnm, bnv, canvas2);
    conv_mfma<true><<<dim3(7, 100, 2), 512, 0, stream>>>(
        canvas2, cwb + 9 * 16384, bng + 128, bnb + 128, bnm + 128, bnv + 128, (float*)d_out);
}

// Round 5
// 3120.909 us; speedup vs baseline: 1.1346x; 1.1346x over previous
//
#include <hip/hip_runtime.h>
#include <math.h>

#define NVOX 60000

typedef __attribute__((ext_vector_type(8))) short short8v;            // 8 bf16 raw
typedef __attribute__((ext_vector_type(8))) unsigned short ushort8v;  // 8 bf16 raw
typedef __attribute__((ext_vector_type(4))) float f32x4;

static __device__ __forceinline__ unsigned short f2bf(float f) {
    unsigned u = __float_as_uint(f);
    unsigned r = (u + 0x7fffu + ((u >> 16) & 1u)) >> 16;
    return (unsigned short)r;
}
static __device__ __forceinline__ float bf2f(unsigned short h) {
    return __uint_as_float(((unsigned)h) << 16);
}
// async global->LDS 16B per lane: dest = lds_base + lane*16 (wave-uniform base)
static __device__ __forceinline__ void gll16(const unsigned short* g, unsigned short* l) {
    __builtin_amdgcn_global_load_lds(
        (const __attribute__((address_space(1))) unsigned*)g,
        (__attribute__((address_space(3))) unsigned*)l,
        16, 0, 0);
}

// ---------------------------------------------------------------- pos embed (bf16 out)
__global__ __launch_bounds__(256) void pos_kernel(const float* __restrict__ ciw,
                                                  unsigned short* __restrict__ pos) {
    int idx = blockIdx.x * 256 + threadIdx.x;
    if (idx >= NVOX * 128) return;
    int n = idx >> 7, d = idx & 127;
    int c = d >> 6, t = (d & 63) >> 1;
    float xy = ciw[n * 2 + c] - 6.0f;
    float inv = exp2f((float)t * (13.287712379549449f / 32.0f)); // 10000^(t/32)
    float e = xy / inv;
    pos[idx] = f2bf((d & 1) ? cosf(e) : sinf(e));
}

// ------------------------------------------------------- fp32 -> bf16 convert
__global__ __launch_bounds__(256) void cvt_bf16(const float* __restrict__ in,
                                                unsigned short* __restrict__ out, int n) {
    int idx = blockIdx.x * 256 + threadIdx.x;
    if (idx < n) out[idx] = f2bf(in[idx]);
}

// -------------------------------------------- feat init: f32 copy + bf16 shadow
__global__ __launch_bounds__(256) void feat_init(const float* __restrict__ vf,
                                                 float* __restrict__ feat,
                                                 unsigned short* __restrict__ featb) {
    int idx = blockIdx.x * 256 + threadIdx.x;
    if (idx >= NVOX * 128) return;
    float v = vf[idx];
    feat[idx] = v;
    featb[idx] = f2bf(v);
}

// ----------------------------------------- MFMA GEMM: C = A*W^T + b (+variants)
// A bf16 [M,KTOT]; W bf16 [N,KTOT]; optional A+=Aadd (bf16, K=128) for
// col-blocks < add_nblk; C f32/bf16 (+GELU); LNF: fused residual+LN epilogue
// (N==128, gridDim.y==1): feat = LN(feat + A@W^T + b)*g + b2, also writes featb.
template<int KTOT, bool ADD, bool GELU, bool CBF16, bool LNF>
__global__ __launch_bounds__(256) void gemm_mfma(
    const unsigned short* __restrict__ A, const unsigned short* __restrict__ Aadd, int add_nblk,
    const unsigned short* __restrict__ W, const float* __restrict__ bias,
    void* __restrict__ Cp, int M, int ldc,
    float* __restrict__ feat, unsigned short* __restrict__ featb,
    const float* __restrict__ lng, const float* __restrict__ lnb)
{
    __shared__ unsigned short As[128 * 64];
    __shared__ unsigned short Ws[128 * 64];
    __shared__ float2 lnsum[128][2];
    const int tid = threadIdx.x;
    const int lane = tid & 63, wave = tid >> 6;
    const int wr = wave >> 1, wc = wave & 1;
    const int llo = lane & 15, lhi = lane >> 4;
    const int m0 = blockIdx.x * 128;
    const int n0 = blockIdx.y * 128;
    const bool addp = ADD && ((int)blockIdx.y < add_nblk);
    const int gr = lane >> 3;           // row within 8-row group
    const int gc = (lane & 7) ^ gr;     // pre-swizzled source chunk
    f32x4 acc[4][4] = {};

    for (int k0 = 0; k0 < KTOT; k0 += 64) {
        // ---- stage W via async global->LDS (source pre-swizzled, dest linear)
        #pragma unroll
        for (int p = 0; p < 4; ++p) {
            int r0 = wave * 32 + p * 8;
            gll16(W + (size_t)(n0 + r0 + gr) * KTOT + k0 + gc * 8, &Ws[r0 * 64]);
        }
        if (!addp) {
            #pragma unroll
            for (int p = 0; p < 4; ++p) {
                int r0 = wave * 32 + p * 8;
                gll16(A + (size_t)(m0 + r0 + gr) * KTOT + k0 + gc * 8, &As[r0 * 64]);
            }
        } else {
            #pragma unroll
            for (int p = 0; p < 4; ++p) {
                int c = tid + p * 256;
                int r = c >> 3, c16 = c & 7;
                int m = m0 + r;
                short8v av = {};
                if (m < M) {
                    ushort8v fa = *reinterpret_cast<const ushort8v*>(A + (size_t)m * KTOT + k0 + c16 * 8);
                    ushort8v pa = *reinterpret_cast<const ushort8v*>(Aadd + (size_t)m * 128 + k0 + c16 * 8);
                    #pragma unroll
                    for (int q = 0; q < 8; ++q) av[q] = (short)f2bf(bf2f(fa[q]) + bf2f(pa[q]));
                }
                *reinterpret_cast<short8v*>((char*)As + r * 128 + ((c16 * 16) ^ ((r & 7) << 4))) = av;
            }
        }
        __syncthreads();
        #pragma unroll
        for (int kk = 0; kk < 2; ++kk) {
            int kb = kk * 64 + lhi * 16;
            short8v af[4], bf[4];
            #pragma unroll
            for (int i = 0; i < 4; ++i) {
                int r = wr * 64 + i * 16 + llo;
                af[i] = *reinterpret_cast<const short8v*>((const char*)As + r * 128 + (kb ^ ((r & 7) << 4)));
                int cc = wc * 64 + i * 16 + llo;
                bf[i] = *reinterpret_cast<const short8v*>((const char*)Ws + cc * 128 + (kb ^ ((cc & 7) << 4)));
            }
            #pragma unroll
            for (int i = 0; i < 4; ++i)
                #pragma unroll
                for (int j = 0; j < 4; ++j)
                    acc[i][j] = __builtin_amdgcn_mfma_f32_16x16x32_bf16(af[i], bf[j], acc[i][j], 0, 0, 0);
        }
        __syncthreads();
    }

    if (LNF) {
        // residual + LN: pass 1 computes x = feat + acc + bias -> stored back in acc
        float s1[4][4] = {}, s2[4][4] = {};
        #pragma unroll
        for (int i = 0; i < 4; ++i)
            #pragma unroll
            for (int rg = 0; rg < 4; ++rg) {
                int m = m0 + wr * 64 + i * 16 + lhi * 4 + rg;
                if (m < M) {
                    #pragma unroll
                    for (int j = 0; j < 4; ++j) {
                        int n = wc * 64 + j * 16 + llo;
                        float x = feat[(size_t)m * 128 + n] + acc[i][j][rg] + bias[n];
                        acc[i][j][rg] = x;
                        s1[i][rg] += x; s2[i][rg] += x * x;
                    }
                }
            }
        #pragma unroll
        for (int i = 0; i < 4; ++i)
            #pragma unroll
            for (int rg = 0; rg < 4; ++rg) {
                #pragma unroll
                for (int off = 1; off < 16; off <<= 1) {
                    s1[i][rg] += __shfl_xor(s1[i][rg], off);
                    s2[i][rg] += __shfl_xor(s2[i][rg], off);
                }
                if (llo == 0)
                    lnsum[wr * 64 + i * 16 + lhi * 4 + rg][wc] = make_float2(s1[i][rg], s2[i][rg]);
            }
        __syncthreads();
        #pragma unroll
        for (int i = 0; i < 4; ++i)
            #pragma unroll
            for (int rg = 0; rg < 4; ++rg) {
                int r = wr * 64 + i * 16 + lhi * 4 + rg;
                int m = m0 + r;
                if (m >= M) continue;
                float2 a0 = lnsum[r][0], a1 = lnsum[r][1];
                float mu = (a0.x + a1.x) * 0.0078125f;
                float var = fmaxf((a0.y + a1.y) * 0.0078125f - mu * mu, 0.f);
                float inv = rsqrtf(var + 1e-5f);
                #pragma unroll
                for (int j = 0; j < 4; ++j) {
                    int n = wc * 64 + j * 16 + llo;
                    float v = (acc[i][j][rg] - mu) * inv * lng[n] + lnb[n];
                    feat[(size_t)m * 128 + n] = v;
                    featb[(size_t)m * 128 + n] = f2bf(v);
                }
            }
    } else {
        #pragma unroll
        for (int j = 0; j < 4; ++j) {
            int n = n0 + wc * 64 + j * 16 + llo;
            float bn = bias[n];
            #pragma unroll
            for (int i = 0; i < 4; ++i) {
                #pragma unroll
                for (int rg = 0; rg < 4; ++rg) {
                    int m = m0 + wr * 64 + i * 16 + lhi * 4 + rg;
                    if (m < M) {
                        float v = acc[i][j][rg] + bn;
                        if (GELU) v = 0.5f * v * (1.0f + erff(v * 0.7071067811865475f));
                        if (CBF16) ((unsigned short*)Cp)[(size_t)m * ldc + n] = f2bf(v);
                        else       ((float*)Cp)[(size_t)m * ldc + n] = v;
                    }
                }
            }
        }
    }
}

// ------------------------------------------------------- windowed attention (bf16 qkv)
template<int CAPT, int HG>
__global__ __launch_bounds__(256) void attn_kernel(
    const unsigned short* __restrict__ qkv, const int* __restrict__ vlist, int nvox,
    unsigned short* __restrict__ oout)
{
    __shared__ float Ks[CAPT][HG * 16];
    __shared__ float Vs[CAPT][HG * 16];
    __shared__ int vl[CAPT];
    const int w = blockIdx.x;
    const int hb = blockIdx.y * HG;
    const int tid = threadIdx.x;
    const int T = min(CAPT, nvox - w * CAPT);
    if (tid < T) vl[tid] = vlist[w * CAPT + tid];
    constexpr int R8 = HG * 2;
    for (int idx = tid; idx < T * R8; idx += 256) {
        int t = idx / R8, c8 = (idx % R8) * 8;
        int vox = vlist[w * CAPT + t];
        const unsigned short* base = qkv + (size_t)vox * 384 + hb * 16 + c8;
        ushort8v kv = *reinterpret_cast<const ushort8v*>(base + 128);
        ushort8v vv = *reinterpret_cast<const ushort8v*>(base + 256);
        #pragma unroll
        for (int q = 0; q < 8; ++q) { Ks[t][c8 + q] = bf2f(kv[q]); Vs[t][c8 + q] = bf2f(vv[q]); }
    }
    __syncthreads();
    const int ITEMS = T * HG;
    for (int item = tid; item < ITEMS; item += 256) {
        int h = item & (HG - 1);
        int q = item / HG;
        int vq = vl[q];
        const unsigned short* qb = qkv + (size_t)vq * 384 + (hb + h) * 16;
        ushort8v qa = *reinterpret_cast<const ushort8v*>(qb);
        ushort8v qc = *reinterpret_cast<const ushort8v*>(qb + 8);
        float4 q0 = make_float4(bf2f(qa[0]), bf2f(qa[1]), bf2f(qa[2]), bf2f(qa[3]));
        float4 q1 = make_float4(bf2f(qa[4]), bf2f(qa[5]), bf2f(qa[6]), bf2f(qa[7]));
        float4 q2 = make_float4(bf2f(qc[0]), bf2f(qc[1]), bf2f(qc[2]), bf2f(qc[3]));
        float4 q3 = make_float4(bf2f(qc[4]), bf2f(qc[5]), bf2f(qc[6]), bf2f(qc[7]));
        float mx = -INFINITY, l = 0.f;
        float4 o0 = make_float4(0,0,0,0), o1 = o0, o2 = o0, o3 = o0;
        for (int t = 0; t < T; ++t) {
            const float4* kr = reinterpret_cast<const float4*>(&Ks[t][h * 16]);
            float4 k0 = kr[0], k1 = kr[1], k2 = kr[2], k3 = kr[3];
            float s = q0.x*k0.x + q0.y*k0.y + q0.z*k0.z + q0.w*k0.w
                    + q1.x*k1.x + q1.y*k1.y + q1.z*k1.z + q1.w*k1.w
                    + q2.x*k2.x + q2.y*k2.y + q2.z*k2.z + q2.w*k2.w
                    + q3.x*k3.x + q3.y*k3.y + q3.z*k3.z + q3.w*k3.w;
            s *= 0.25f;
            float mo = mx;
            mx = fmaxf(mx, s);
            float cc = __expf(mo - mx);
            float p  = __expf(s - mx);
            l = l * cc + p;
            const float4* vr = reinterpret_cast<const float4*>(&Vs[t][h * 16]);
            float4 v0 = vr[0], v1 = vr[1], v2 = vr[2], v3 = vr[3];
            o0.x = o0.x*cc + p*v0.x; o0.y = o0.y*cc + p*v0.y; o0.z = o0.z*cc + p*v0.z; o0.w = o0.w*cc + p*v0.w;
            o1.x = o1.x*cc + p*v1.x; o1.y = o1.y*cc + p*v1.y; o1.z = o1.z*cc + p*v1.z; o1.w = o1.w*cc + p*v1.w;
            o2.x = o2.x*cc + p*v2.x; o2.y = o2.y*cc + p*v2.y; o2.z = o2.z*cc + p*v2.z; o2.w = o2.w*cc + p*v2.w;
            o3.x = o3.x*cc + p*v3.x; o3.y = o3.y*cc + p*v3.y; o3.z = o3.z*cc + p*v3.z; o3.w = o3.w*cc + p*v3.w;
        }
        float rl = 1.0f / l;
        ushort8v r0, r1;
        r0[0]=f2bf(o0.x*rl); r0[1]=f2bf(o0.y*rl); r0[2]=f2bf(o0.z*rl); r0[3]=f2bf(o0.w*rl);
        r0[4]=f2bf(o1.x*rl); r0[5]=f2bf(o1.y*rl); r0[6]=f2bf(o1.z*rl); r0[7]=f2bf(o1.w*rl);
        r1[0]=f2bf(o2.x*rl); r1[1]=f2bf(o2.y*rl); r1[2]=f2bf(o2.z*rl); r1[3]=f2bf(o2.w*rl);
        r1[4]=f2bf(o3.x*rl); r1[5]=f2bf(o3.y*rl); r1[6]=f2bf(o3.z*rl); r1[7]=f2bf(o3.w*rl);
        unsigned short* op = oout + (size_t)vq * 128 + (hb + h) * 16;
        *reinterpret_cast<ushort8v*>(op) = r0;
        *reinterpret_cast<ushort8v*>(op + 8) = r1;
    }
}

// ---------------------------------------- BEV scatter into padded canvas (bf16)
__global__ __launch_bounds__(256) void scatter_kernel(const float* __restrict__ feat,
    const int* __restrict__ coors, unsigned short* __restrict__ canvas)
{
    int idx = blockIdx.x * 256 + threadIdx.x;
    if (idx >= NVOX * 16) return;
    int n = idx >> 4, c8 = (idx & 15) << 3;
    int b = coors[n * 4], y = coors[n * 4 + 2], x = coors[n * 4 + 3];
    const float* src = feat + (size_t)n * 128 + c8;
    float4 u0 = *reinterpret_cast<const float4*>(src);
    float4 u1 = *reinterpret_cast<const float4*>(src + 4);
    ushort8v v;
    v[0]=f2bf(u0.x); v[1]=f2bf(u0.y); v[2]=f2bf(u0.z); v[3]=f2bf(u0.w);
    v[4]=f2bf(u1.x); v[5]=f2bf(u1.y); v[6]=f2bf(u1.z); v[7]=f2bf(u1.w);
    size_t p = (((size_t)b * 404 + y + 2) * 404 + x + 2) * 128 + c8;
    *reinterpret_cast<ushort8v*>(canvas + p) = v;
}

// ------------------- conv weight re-layout -> bf16 [i][ky*3+kx][cout][cin]
__global__ __launch_bounds__(256) void wtrans_kernel(const float* __restrict__ cw,
                                                     unsigned short* __restrict__ wbuf)
{
    int idx = blockIdx.x * 256 + threadIdx.x;
    if (idx >= 2 * 9 * 128 * 128) return;
    int ci = idx & 127;
    int co = (idx >> 7) & 127;
    int kk = (idx >> 14) % 9;
    int i  = idx / (9 * 16384);
    wbuf[idx] = f2bf(cw[(((size_t)i * 128 + co) * 128 + ci) * 9 + kk]);
}

// ---------------- 3x3 dilated(2) conv + BN + ReLU, LDS-A + reg-prefetched-B
// in: padded NHWC bf16 [2][404][404][128].  Block: 64px x 128co x 4y,
// 512 thr = 8 waves (2px x 2co x 2y).  A staged in LDS (4-bit XOR swizzle),
// weights prefetched one tap ahead into registers (16 b128 per tap).
template<bool NCHW_OUT>
__global__ __launch_bounds__(512, 2) void conv_mfma(
    const unsigned short* __restrict__ in, const unsigned short* __restrict__ wbuf,
    const float* __restrict__ g, const float* __restrict__ bsh,
    const float* __restrict__ bm, const float* __restrict__ bv,
    void* __restrict__ out)
{
    __shared__ unsigned short As[8 * 68 * 128];   // 139264 B
    const int tid = threadIdx.x;
    const int lane = tid & 63, wave = tid >> 6;
    const int pxg = wave & 1, cog = (wave >> 1) & 1, yg = wave >> 2;
    const int llo = lane & 15, lhi = lane >> 4;
    const int x0 = blockIdx.x * 64, y0 = blockIdx.y * 4, b = blockIdx.z;
    const size_t rowstride = 404 * 128;

    // ---- stage 8 padded rows [y0 .. y0+7] x 68 cols [x0 .. x0+67], swizzled
    if (x0 + 67 < 404) {
        // interior: per-lane-source global_load_lds, linear LDS dest
        const unsigned short* rowp = in + ((size_t)b * 404 + y0 + wave) * rowstride;
        #pragma unroll
        for (int it = 0; it < 17; ++it) {
            int xi = it * 4 + (lane >> 4);
            int srcc = (lane & 15) ^ (xi & 15);
            gll16(rowp + (size_t)(x0 + xi) * 128 + srcc * 8,
                  &As[(wave * 68 + it * 4) * 128]);
        }
    } else {
        for (int c = tid; c < 8 * 68 * 16; c += 512) {
            int r = c / (68 * 16);
            int rem = c % (68 * 16);
            int xi = rem >> 4, c16 = rem & 15;
            int xx = x0 + xi;
            short8v v = {};
            if (xx < 404)
                v = *reinterpret_cast<const short8v*>(
                    in + ((size_t)b * 404 + y0 + r) * rowstride + (size_t)xx * 128
                       + ((c16 ^ (xi & 15)) * 8));
            *reinterpret_cast<short8v*>((char*)As + (r * 68 + xi) * 256 + c16 * 16) = v;
        }
    }
    __syncthreads();

    // ---- weight prefetch ping-pong + MFMA
    const unsigned short* wbase = wbuf + cog * 8192;
    short8v B0[16], B1[16];
    #pragma unroll
    for (int kk = 0; kk < 4; ++kk)
        #pragma unroll
        for (int j = 0; j < 4; ++j)
            B0[kk * 4 + j] = *reinterpret_cast<const short8v*>(
                wbase + (j * 16 + llo) * 128 + kk * 32 + lhi * 8);

    f32x4 acc[2][2][4] = {};    // [dy][i(px)][j(co)]
    #pragma unroll
    for (int tap = 0; tap < 9; ++tap) {
        if (tap < 8) {
            const unsigned short* wt = wbase + (size_t)(tap + 1) * 16384;
            short8v* Bn = (tap & 1) ? B0 : B1;
            #pragma unroll
            for (int kk = 0; kk < 4; ++kk)
                #pragma unroll
                for (int j = 0; j < 4; ++j)
                    Bn[kk * 4 + j] = *reinterpret_cast<const short8v*>(
                        wt + (j * 16 + llo) * 128 + kk * 32 + lhi * 8);
        }
        const short8v* Bc = (tap & 1) ? B1 : B0;
        const int ky = tap / 3, kx = tap % 3;
        #pragma unroll
        for (int kk = 0; kk < 4; ++kk) {
            short8v a[2][2];
            #pragma unroll
            for (int dy = 0; dy < 2; ++dy)
                #pragma unroll
                for (int i = 0; i < 2; ++i) {
                    int xi = pxg * 32 + i * 16 + llo + 2 * kx;
                    int row = yg * 2 + dy + 2 * ky;
                    int chunk = (kk * 4 + lhi) ^ (xi & 15);
                    a[dy][i] = *reinterpret_cast<const short8v*>(
                        (const char*)As + (row * 68 + xi) * 256 + chunk * 16);
                }
            #pragma unroll
            for (int dy = 0; dy < 2; ++dy)
                #pragma unroll
                for (int i = 0; i < 2; ++i)
                    #pragma unroll
                    for (int j = 0; j < 4; ++j)
                        acc[dy][i][j] = __builtin_amdgcn_mfma_f32_16x16x32_bf16(
                            a[dy][i], Bc[kk * 4 + j], acc[dy][i][j], 0, 0, 0);
        }
    }

    #pragma unroll
    for (int j = 0; j < 4; ++j) {
        int co = cog * 64 + j * 16 + llo;
        float scale = rsqrtf(bv[co] + 1e-3f) * g[co];
        float shift = bsh[co] - bm[co] * scale;
        #pragma unroll
        for (int dy = 0; dy < 2; ++dy) {
            int y = y0 + yg * 2 + dy;
            #pragma unroll
            for (int i = 0; i < 2; ++i) {
                #pragma unroll
                for (int rg = 0; rg < 4; ++rg) {
                    int px = x0 + pxg * 32 + i * 16 + lhi * 4 + rg;
                    if (px < 400) {
                        float v = fmaxf(acc[dy][i][j][rg] * scale + shift, 0.f);
                        if (NCHW_OUT)
                            ((float*)out)[(((size_t)b * 128 + co) * 400 + y) * 400 + px] = v;
                        else
                            ((unsigned short*)out)[(((size_t)b * 404 + y + 2) * 404 + px + 2) * 128 + co] = f2bf(v);
                    }
                }
            }
        }
    }
}

// ---------------------------------------------------------------- launcher
extern "C" void kernel_launch(void* const* d_in, const int* in_sizes, int n_in,
                              void* d_out, int out_size, void* d_ws, size_t ws_size,
                              hipStream_t stream) {
    const float* voxel_feat = (const float*)d_in[0];
    const int*   coors      = (const int*)d_in[1];
    const float* ciw0       = (const float*)d_in[2];
    const float* ciw1       = (const float*)d_in[3];
    const int* vx[2][2] = {{(const int*)d_in[4], (const int*)d_in[6]},
                           {(const int*)d_in[8], (const int*)d_in[10]}};
    const float* ipw = (const float*)d_in[12];
    const float* ipb = (const float*)d_in[13];
    const float* ow  = (const float*)d_in[14];
    const float* obp = (const float*)d_in[15];
    const float* l1w = (const float*)d_in[16];
    const float* l1b = (const float*)d_in[17];
    const float* l2w = (const float*)d_in[18];
    const float* l2b = (const float*)d_in[19];
    const float* g1  = (const float*)d_in[20];
    const float* b1  = (const float*)d_in[21];
    const float* g2  = (const float*)d_in[22];
    const float* b2  = (const float*)d_in[23];
    const float* cw  = (const float*)d_in[24];
    const float* bng = (const float*)d_in[25];
    const float* bnb = (const float*)d_in[26];
    const float* bnm = (const float*)d_in[27];
    const float* bnv = (const float*)d_in[28];

    float* F = (float*)d_ws;
    unsigned short* W0   = (unsigned short*)F;           // bf16 weights: 1,867,776
    unsigned short* ipwb = W0;                           // 589824
    unsigned short* owb  = W0 + 589824;                  // 196608
    unsigned short* l1wb = W0 + 786432;                  // 393216
    unsigned short* l2wb = W0 + 1179648;                 // 393216
    unsigned short* cwb  = W0 + 1572864;                 // 294912
    float* feat = F + 940000;                            // 7.68M f32
    unsigned short* featb = (unsigned short*)(F + 8620000);   // 7.68M bf16
    unsigned short* pos0  = (unsigned short*)(F + 12460000);  // 7.68M bf16
    unsigned short* pos1  = (unsigned short*)(F + 16300000);
    unsigned short* obufb = (unsigned short*)(F + 20140000);
    unsigned short* hbufb = (unsigned short*)(F + 23980000);  // 15.36M bf16
    // conv phase (pos/obuf/hbuf dead; feat still live for scatter):
    unsigned short* canvas1 = (unsigned short*)(F + 12460000);  // padded 41.78M bf16
    unsigned short* canvas2 = (unsigned short*)(F + 33360000);  // padded 41.78M bf16
    unsigned short* qkvb = (unsigned short*)d_out;       // 23.04M bf16 scratch

    feat_init<<<30000, 256, 0, stream>>>(voxel_feat, feat, featb);
    pos_kernel<<<30000, 256, 0, stream>>>(ciw0, pos0);
    pos_kernel<<<30000, 256, 0, stream>>>(ciw1, pos1);
    cvt_bf16<<<(589824 + 255) / 256, 256, 0, stream>>>(ipw, ipwb, 589824);
    cvt_bf16<<<(196608 + 255) / 256, 256, 0, stream>>>(ow,  owb,  196608);
    cvt_bf16<<<(393216 + 255) / 256, 256, 0, stream>>>(l1w, l1wb, 393216);
    cvt_bf16<<<(393216 + 255) / 256, 256, 0, stream>>>(l2w, l2wb, 393216);
    wtrans_kernel<<<(2 * 9 * 16384 + 255) / 256, 256, 0, stream>>>(cw, cwb);

    for (int li = 0; li < 12; ++li) {
        int s = li & 1;
        const unsigned short* pos = s ? pos1 : pos0;
        // QKV: q,k col-blocks get +pos (reg-staged); v block pure gll
        gemm_mfma<128, true, false, true, false><<<dim3(469, 3), 256, 0, stream>>>(
            featb, pos, 2, ipwb + (size_t)li * 49152, ipb + li * 384, qkvb, NVOX, 384,
            nullptr, nullptr, nullptr, nullptr);
        attn_kernel<25, 8><<<dim3(960, 1), 256, 0, stream>>>(qkvb, vx[s][0], 24000, obufb);
        attn_kernel<100, 4><<<dim3(360, 2), 256, 0, stream>>>(qkvb, vx[s][1], 36000, obufb);
        // out-proj + residual + LN1 fused
        gemm_mfma<128, false, false, false, true><<<dim3(469, 1), 256, 0, stream>>>(
            obufb, nullptr, 0, owb + (size_t)li * 16384, obp + li * 128, nullptr, NVOX, 128,
            feat, featb, g1 + li * 128, b1 + li * 128);
        // FFN1 + GELU, bf16 out
        gemm_mfma<128, false, true, true, false><<<dim3(469, 2), 256, 0, stream>>>(
            featb, nullptr, 0, l1wb + (size_t)li * 32768, l1b + li * 256, hbufb, NVOX, 256,
            nullptr, nullptr, nullptr, nullptr);
        // FFN2 + residual + LN2 fused
        gemm_mfma<256, false, false, false, true><<<dim3(469, 1), 256, 0, stream>>>(
            hbufb, nullptr, 0, l2wb + (size_t)li * 32768, l2b + li * 128, nullptr, NVOX, 128,
            feat, featb, g2 + li * 128, b2 + li * 128);
    }

    // BEV: zero both padded canvases (contiguous), scatter, conv1, conv2
    hipMemsetAsync(canvas1, 0, (size_t)(20900000 + 8383296 + 41783296) * 2, stream);
    scatter_kernel<<<(NVOX * 16 + 255) / 256, 256, 0, stream>>>(feat, coors, canvas1);
    conv_mfma<false><<<dim3(7, 100, 2), 512, 0, stream>>>(
        canvas1, cwb, bng, bnb, bnm, bnv, canvas2);
    conv_mfma<true><<<dim3(7, 100, 2), 512, 0, stream>>>(
        canvas2, cwb + 9 * 16384, bng + 128, bnb + 128, bnm + 128, bnv + 128, (float*)d_out);
}

// Round 6
// 2737.722 us; speedup vs baseline: 1.2934x; 1.1400x over previous
//
#include <hip/hip_runtime.h>
#include <math.h>

#define NVOX 60000

typedef __attribute__((ext_vector_type(8))) short short8v;            // 8 bf16 raw
typedef __attribute__((ext_vector_type(8))) unsigned short ushort8v;  // 8 bf16 raw
typedef __attribute__((ext_vector_type(4))) float f32x4;

static __device__ __forceinline__ unsigned short f2bf(float f) {
    unsigned u = __float_as_uint(f);
    unsigned r = (u + 0x7fffu + ((u >> 16) & 1u)) >> 16;
    return (unsigned short)r;
}
static __device__ __forceinline__ float bf2f(unsigned short h) {
    return __uint_as_float(((unsigned)h) << 16);
}
// async global->LDS 16B per lane: dest = lds_base + lane*16 (wave-uniform base)
static __device__ __forceinline__ void gll16(const unsigned short* g, unsigned short* l) {
    __builtin_amdgcn_global_load_lds(
        (const __attribute__((address_space(1))) unsigned*)g,
        (__attribute__((address_space(3))) unsigned*)l,
        16, 0, 0);
}

// ---------------------------------------------------------------- pos embed (bf16 out)
__global__ __launch_bounds__(256) void pos_kernel(const float* __restrict__ ciw,
                                                  unsigned short* __restrict__ pos) {
    int idx = blockIdx.x * 256 + threadIdx.x;
    if (idx >= NVOX * 128) return;
    int n = idx >> 7, d = idx & 127;
    int c = d >> 6, t = (d & 63) >> 1;
    float xy = ciw[n * 2 + c] - 6.0f;
    float inv = exp2f((float)t * (13.287712379549449f / 32.0f)); // 10000^(t/32)
    float e = xy / inv;
    pos[idx] = f2bf((d & 1) ? cosf(e) : sinf(e));
}

// ------------------------------------------------------- fp32 -> bf16 convert
__global__ __launch_bounds__(256) void cvt_bf16(const float* __restrict__ in,
                                                unsigned short* __restrict__ out, int n) {
    int idx = blockIdx.x * 256 + threadIdx.x;
    if (idx < n) out[idx] = f2bf(in[idx]);
}

// -------------------------------------------- feat init: f32 copy + bf16 shadow
__global__ __launch_bounds__(256) void feat_init(const float* __restrict__ vf,
                                                 float* __restrict__ feat,
                                                 unsigned short* __restrict__ featb) {
    int idx = blockIdx.x * 256 + threadIdx.x;
    if (idx >= NVOX * 128) return;
    float v = vf[idx];
    feat[idx] = v;
    featb[idx] = f2bf(v);
}

// ----------------------------------------- MFMA GEMM: C = A*W^T + b (+variants)
// A bf16 [M,KTOT]; W bf16 [N,KTOT]; optional A+=Aadd (bf16, K=128) for
// col-blocks < add_nblk; CBF16 out staged via LDS for coalesced ushort8 stores;
// LNF: fused residual+LN epilogue (N==128, gridDim.y==1).
template<int KTOT, bool ADD, bool GELU, bool CBF16, bool LNF>
__global__ __launch_bounds__(256) void gemm_mfma(
    const unsigned short* __restrict__ A, const unsigned short* __restrict__ Aadd, int add_nblk,
    const unsigned short* __restrict__ W, const float* __restrict__ bias,
    void* __restrict__ Cp, int M, int ldc,
    float* __restrict__ feat, unsigned short* __restrict__ featb,
    const float* __restrict__ lng, const float* __restrict__ lnb)
{
    __shared__ unsigned short smem[128 * 128];   // As(16KB) + Ws(16KB), reused as Cs(32KB)
    __shared__ float2 lnsum[128][2];
    unsigned short* As = smem;
    unsigned short* Ws = smem + 128 * 64;
    const int tid = threadIdx.x;
    const int lane = tid & 63, wave = tid >> 6;
    const int wr = wave >> 1, wc = wave & 1;
    const int llo = lane & 15, lhi = lane >> 4;
    const int m0 = blockIdx.x * 128;
    const int n0 = blockIdx.y * 128;
    const bool addp = ADD && ((int)blockIdx.y < add_nblk);
    const int gr = lane >> 3;           // row within 8-row group
    const int gc = (lane & 7) ^ gr;     // pre-swizzled source chunk
    f32x4 acc[4][4] = {};

    for (int k0 = 0; k0 < KTOT; k0 += 64) {
        #pragma unroll
        for (int p = 0; p < 4; ++p) {
            int r0 = wave * 32 + p * 8;
            gll16(W + (size_t)(n0 + r0 + gr) * KTOT + k0 + gc * 8, &Ws[r0 * 64]);
        }
        if (!addp) {
            #pragma unroll
            for (int p = 0; p < 4; ++p) {
                int r0 = wave * 32 + p * 8;
                gll16(A + (size_t)(m0 + r0 + gr) * KTOT + k0 + gc * 8, &As[r0 * 64]);
            }
        } else {
            #pragma unroll
            for (int p = 0; p < 4; ++p) {
                int c = tid + p * 256;
                int r = c >> 3, c16 = c & 7;
                int m = m0 + r;
                short8v av = {};
                if (m < M) {
                    ushort8v fa = *reinterpret_cast<const ushort8v*>(A + (size_t)m * KTOT + k0 + c16 * 8);
                    ushort8v pa = *reinterpret_cast<const ushort8v*>(Aadd + (size_t)m * 128 + k0 + c16 * 8);
                    #pragma unroll
                    for (int q = 0; q < 8; ++q) av[q] = (short)f2bf(bf2f(fa[q]) + bf2f(pa[q]));
                }
                *reinterpret_cast<short8v*>((char*)As + r * 128 + ((c16 * 16) ^ ((r & 7) << 4))) = av;
            }
        }
        __syncthreads();
        #pragma unroll
        for (int kk = 0; kk < 2; ++kk) {
            int kb = kk * 64 + lhi * 16;
            short8v af[4], bf[4];
            #pragma unroll
            for (int i = 0; i < 4; ++i) {
                int r = wr * 64 + i * 16 + llo;
                af[i] = *reinterpret_cast<const short8v*>((const char*)As + r * 128 + (kb ^ ((r & 7) << 4)));
                int cc = wc * 64 + i * 16 + llo;
                bf[i] = *reinterpret_cast<const short8v*>((const char*)Ws + cc * 128 + (kb ^ ((cc & 7) << 4)));
            }
            #pragma unroll
            for (int i = 0; i < 4; ++i)
                #pragma unroll
                for (int j = 0; j < 4; ++j)
                    acc[i][j] = __builtin_amdgcn_mfma_f32_16x16x32_bf16(af[i], bf[j], acc[i][j], 0, 0, 0);
        }
        __syncthreads();
    }

    if (LNF) {
        // residual + LN: pass 1 computes x = feat + acc + bias -> stored back in acc
        float s1[4][4] = {}, s2[4][4] = {};
        #pragma unroll
        for (int i = 0; i < 4; ++i)
            #pragma unroll
            for (int rg = 0; rg < 4; ++rg) {
                int m = m0 + wr * 64 + i * 16 + lhi * 4 + rg;
                if (m < M) {
                    #pragma unroll
                    for (int j = 0; j < 4; ++j) {
                        int n = wc * 64 + j * 16 + llo;
                        float x = feat[(size_t)m * 128 + n] + acc[i][j][rg] + bias[n];
                        acc[i][j][rg] = x;
                        s1[i][rg] += x; s2[i][rg] += x * x;
                    }
                }
            }
        #pragma unroll
        for (int i = 0; i < 4; ++i)
            #pragma unroll
            for (int rg = 0; rg < 4; ++rg) {
                #pragma unroll
                for (int off = 1; off < 16; off <<= 1) {
                    s1[i][rg] += __shfl_xor(s1[i][rg], off);
                    s2[i][rg] += __shfl_xor(s2[i][rg], off);
                }
                if (llo == 0)
                    lnsum[wr * 64 + i * 16 + lhi * 4 + rg][wc] = make_float2(s1[i][rg], s2[i][rg]);
            }
        __syncthreads();
        #pragma unroll
        for (int i = 0; i < 4; ++i)
            #pragma unroll
            for (int rg = 0; rg < 4; ++rg) {
                int r = wr * 64 + i * 16 + lhi * 4 + rg;
                int m = m0 + r;
                if (m >= M) continue;
                float2 a0 = lnsum[r][0], a1 = lnsum[r][1];
                float mu = (a0.x + a1.x) * 0.0078125f;
                float var = fmaxf((a0.y + a1.y) * 0.0078125f - mu * mu, 0.f);
                float inv = rsqrtf(var + 1e-5f);
                #pragma unroll
                for (int j = 0; j < 4; ++j) {
                    int n = wc * 64 + j * 16 + llo;
                    float v = (acc[i][j][rg] - mu) * inv * lng[n] + lnb[n];
                    feat[(size_t)m * 128 + n] = v;
                    featb[(size_t)m * 128 + n] = f2bf(v);
                }
            }
    } else if (CBF16) {
        // stage bf16 C tile in LDS, then coalesced ushort8 stores
        #pragma unroll
        for (int j = 0; j < 4; ++j) {
            int nl = wc * 64 + j * 16 + llo;
            float bn = bias[n0 + nl];
            #pragma unroll
            for (int i = 0; i < 4; ++i)
                #pragma unroll
                for (int rg = 0; rg < 4; ++rg) {
                    float v = acc[i][j][rg] + bn;
                    if (GELU) v = 0.5f * v * (1.0f + erff(v * 0.7071067811865475f));
                    smem[(wr * 64 + i * 16 + lhi * 4 + rg) * 128 + nl] = f2bf(v);
                }
        }
        __syncthreads();
        unsigned short* C = (unsigned short*)Cp;
        #pragma unroll
        for (int c = 0; c < 8; ++c) {
            int idx = tid + c * 256;
            int r = idx >> 4, ch = idx & 15;
            if (m0 + r < M)
                *reinterpret_cast<ushort8v*>(C + (size_t)(m0 + r) * ldc + n0 + ch * 8) =
                    *reinterpret_cast<const ushort8v*>(&smem[r * 128 + ch * 8]);
        }
    } else {
        float* C = (float*)Cp;
        #pragma unroll
        for (int j = 0; j < 4; ++j) {
            int n = n0 + wc * 64 + j * 16 + llo;
            float bn = bias[n];
            #pragma unroll
            for (int i = 0; i < 4; ++i)
                #pragma unroll
                for (int rg = 0; rg < 4; ++rg) {
                    int m = m0 + wr * 64 + i * 16 + lhi * 4 + rg;
                    if (m < M) {
                        float v = acc[i][j][rg] + bn;
                        if (GELU) v = 0.5f * v * (1.0f + erff(v * 0.7071067811865475f));
                        C[(size_t)m * ldc + n] = v;
                    }
                }
        }
    }
}

// ------------------------------------------------------- windowed attention (bf16 qkv)
template<int CAPT, int HG>
__global__ __launch_bounds__(256) void attn_kernel(
    const unsigned short* __restrict__ qkv, const int* __restrict__ vlist, int nvox,
    unsigned short* __restrict__ oout)
{
    __shared__ float Ks[CAPT][HG * 16];
    __shared__ float Vs[CAPT][HG * 16];
    __shared__ int vl[CAPT];
    const int w = blockIdx.x;
    const int hb = blockIdx.y * HG;
    const int tid = threadIdx.x;
    const int T = min(CAPT, nvox - w * CAPT);
    if (tid < T) vl[tid] = vlist[w * CAPT + tid];
    constexpr int R8 = HG * 2;
    for (int idx = tid; idx < T * R8; idx += 256) {
        int t = idx / R8, c8 = (idx % R8) * 8;
        int vox = vlist[w * CAPT + t];
        const unsigned short* base = qkv + (size_t)vox * 384 + hb * 16 + c8;
        ushort8v kv = *reinterpret_cast<const ushort8v*>(base + 128);
        ushort8v vv = *reinterpret_cast<const ushort8v*>(base + 256);
        #pragma unroll
        for (int q = 0; q < 8; ++q) { Ks[t][c8 + q] = bf2f(kv[q]); Vs[t][c8 + q] = bf2f(vv[q]); }
    }
    __syncthreads();
    const int ITEMS = T * HG;
    for (int item = tid; item < ITEMS; item += 256) {
        int h = item & (HG - 1);
        int q = item / HG;
        int vq = vl[q];
        const unsigned short* qb = qkv + (size_t)vq * 384 + (hb + h) * 16;
        ushort8v qa = *reinterpret_cast<const ushort8v*>(qb);
        ushort8v qc = *reinterpret_cast<const ushort8v*>(qb + 8);
        float4 q0 = make_float4(bf2f(qa[0]), bf2f(qa[1]), bf2f(qa[2]), bf2f(qa[3]));
        float4 q1 = make_float4(bf2f(qa[4]), bf2f(qa[5]), bf2f(qa[6]), bf2f(qa[7]));
        float4 q2 = make_float4(bf2f(qc[0]), bf2f(qc[1]), bf2f(qc[2]), bf2f(qc[3]));
        float4 q3 = make_float4(bf2f(qc[4]), bf2f(qc[5]), bf2f(qc[6]), bf2f(qc[7]));
        float mx = -INFINITY, l = 0.f;
        float4 o0 = make_float4(0,0,0,0), o1 = o0, o2 = o0, o3 = o0;
        for (int t = 0; t < T; ++t) {
            const float4* kr = reinterpret_cast<const float4*>(&Ks[t][h * 16]);
            float4 k0 = kr[0], k1 = kr[1], k2 = kr[2], k3 = kr[3];
            float s = q0.x*k0.x + q0.y*k0.y + q0.z*k0.z + q0.w*k0.w
                    + q1.x*k1.x + q1.y*k1.y + q1.z*k1.z + q1.w*k1.w
                    + q2.x*k2.x + q2.y*k2.y + q2.z*k2.z + q2.w*k2.w
                    + q3.x*k3.x + q3.y*k3.y + q3.z*k3.z + q3.w*k3.w;
            s *= 0.25f;
            float mo = mx;
            mx = fmaxf(mx, s);
            float cc = __expf(mo - mx);
            float p  = __expf(s - mx);
            l = l * cc + p;
            const float4* vr = reinterpret_cast<const float4*>(&Vs[t][h * 16]);
            float4 v0 = vr[0], v1 = vr[1], v2 = vr[2], v3 = vr[3];
            o0.x = o0.x*cc + p*v0.x; o0.y = o0.y*cc + p*v0.y; o0.z = o0.z*cc + p*v0.z; o0.w = o0.w*cc + p*v0.w;
            o1.x = o1.x*cc + p*v1.x; o1.y = o1.y*cc + p*v1.y; o1.z = o1.z*cc + p*v1.z; o1.w = o1.w*cc + p*v1.w;
            o2.x = o2.x*cc + p*v2.x; o2.y = o2.y*cc + p*v2.y; o2.z = o2.z*cc + p*v2.z; o2.w = o2.w*cc + p*v2.w;
            o3.x = o3.x*cc + p*v3.x; o3.y = o3.y*cc + p*v3.y; o3.z = o3.z*cc + p*v3.z; o3.w = o3.w*cc + p*v3.w;
        }
        float rl = 1.0f / l;
        ushort8v r0, r1;
        r0[0]=f2bf(o0.x*rl); r0[1]=f2bf(o0.y*rl); r0[2]=f2bf(o0.z*rl); r0[3]=f2bf(o0.w*rl);
        r0[4]=f2bf(o1.x*rl); r0[5]=f2bf(o1.y*rl); r0[6]=f2bf(o1.z*rl); r0[7]=f2bf(o1.w*rl);
        r1[0]=f2bf(o2.x*rl); r1[1]=f2bf(o2.y*rl); r1[2]=f2bf(o2.z*rl); r1[3]=f2bf(o2.w*rl);
        r1[4]=f2bf(o3.x*rl); r1[5]=f2bf(o3.y*rl); r1[6]=f2bf(o3.z*rl); r1[7]=f2bf(o3.w*rl);
        unsigned short* op = oout + (size_t)vq * 128 + (hb + h) * 16;
        *reinterpret_cast<ushort8v*>(op) = r0;
        *reinterpret_cast<ushort8v*>(op + 8) = r1;
    }
}

// ---------------------------------------- BEV scatter into padded canvas (bf16)
__global__ __launch_bounds__(256) void scatter_kernel(const float* __restrict__ feat,
    const int* __restrict__ coors, unsigned short* __restrict__ canvas)
{
    int idx = blockIdx.x * 256 + threadIdx.x;
    if (idx >= NVOX * 16) return;
    int n = idx >> 4, c8 = (idx & 15) << 3;
    int b = coors[n * 4], y = coors[n * 4 + 2], x = coors[n * 4 + 3];
    const float* src = feat + (size_t)n * 128 + c8;
    float4 u0 = *reinterpret_cast<const float4*>(src);
    float4 u1 = *reinterpret_cast<const float4*>(src + 4);
    ushort8v v;
    v[0]=f2bf(u0.x); v[1]=f2bf(u0.y); v[2]=f2bf(u0.z); v[3]=f2bf(u0.w);
    v[4]=f2bf(u1.x); v[5]=f2bf(u1.y); v[6]=f2bf(u1.z); v[7]=f2bf(u1.w);
    size_t p = (((size_t)b * 404 + y + 2) * 404 + x + 2) * 128 + c8;
    *reinterpret_cast<ushort8v*>(canvas + p) = v;
}

// ----------------------------------------------- zero the halo of a padded canvas
__global__ __launch_bounds__(256) void halo_zero(unsigned short* __restrict__ c) {
    int idx = blockIdx.x * 256 + threadIdx.x;      // 2 * 3216 * 16 chunks
    if (idx >= 2 * 3216 * 16) return;
    int b = idx / (3216 * 16);
    int rem = idx % (3216 * 16);
    int p = rem >> 4, c8 = (rem & 15) * 8;
    const int edge[4] = {0, 1, 402, 403};
    int y, x;
    if (p < 1616) { y = edge[p / 404]; x = p % 404; }
    else { int q = p - 1616; y = 2 + (q >> 2); x = edge[q & 3]; }
    ushort8v z = {};
    *reinterpret_cast<ushort8v*>(c + (((size_t)b * 404 + y) * 404 + x) * 128 + c8) = z;
}

// ------------------- conv weight re-layout -> bf16 [i][ky*3+kx][cout][cin]
__global__ __launch_bounds__(256) void wtrans_kernel(const float* __restrict__ cw,
                                                     unsigned short* __restrict__ wbuf)
{
    int idx = blockIdx.x * 256 + threadIdx.x;
    if (idx >= 2 * 9 * 128 * 128) return;
    int ci = idx & 127;
    int co = (idx >> 7) & 127;
    int kk = (idx >> 14) % 9;
    int i  = idx / (9 * 16384);
    wbuf[idx] = f2bf(cw[(((size_t)i * 128 + co) * 128 + ci) * 9 + kk]);
}

// conv helpers: weight-fragment load + one-tap MFMA (array bound statically at call site)
static __device__ __forceinline__ void loadW(short8v (&B)[16], const unsigned short* wt,
                                             int llo, int lhi) {
    #pragma unroll
    for (int kk = 0; kk < 4; ++kk)
        #pragma unroll
        for (int j = 0; j < 4; ++j)
            B[kk * 4 + j] = *reinterpret_cast<const short8v*>(
                wt + (j * 16 + llo) * 128 + kk * 32 + lhi * 8);
}
static __device__ __forceinline__ void tapCompute(const short8v (&B)[16], f32x4 (&acc)[2][2][4],
                                                  const unsigned short* As, int ky, int kx,
                                                  int pxg, int yg, int llo, int lhi) {
    #pragma unroll
    for (int kk = 0; kk < 4; ++kk) {
        short8v a[2][2];
        #pragma unroll
        for (int dy = 0; dy < 2; ++dy)
            #pragma unroll
            for (int i = 0; i < 2; ++i) {
                int xi = pxg * 32 + i * 16 + llo + 2 * kx;
                int row = yg * 2 + dy + 2 * ky;
                int chunk = (kk * 4 + lhi) ^ (xi & 15);
                a[dy][i] = *reinterpret_cast<const short8v*>(
                    (const char*)As + (row * 68 + xi) * 256 + chunk * 16);
            }
        #pragma unroll
        for (int dy = 0; dy < 2; ++dy)
            #pragma unroll
            for (int i = 0; i < 2; ++i)
                #pragma unroll
                for (int j = 0; j < 4; ++j)
                    acc[dy][i][j] = __builtin_amdgcn_mfma_f32_16x16x32_bf16(
                        a[dy][i], B[kk * 4 + j], acc[dy][i][j], 0, 0, 0);
    }
}

// ---------------- 3x3 dilated(2) conv + BN + ReLU, LDS-A + double-buffered reg weights
template<bool NCHW_OUT>
__global__ __launch_bounds__(512, 2) void conv_mfma(
    const unsigned short* __restrict__ in, const unsigned short* __restrict__ wbuf,
    const float* __restrict__ g, const float* __restrict__ bsh,
    const float* __restrict__ bm, const float* __restrict__ bv,
    void* __restrict__ out)
{
    __shared__ unsigned short As[8 * 68 * 128];   // 139264 B
    const int tid = threadIdx.x;
    const int lane = tid & 63, wave = tid >> 6;
    const int pxg = wave & 1, cog = (wave >> 1) & 1, yg = wave >> 2;
    const int llo = lane & 15, lhi = lane >> 4;
    const int x0 = blockIdx.x * 64, y0 = blockIdx.y * 4, b = blockIdx.z;
    const size_t rowstride = 404 * 128;

    // ---- stage 8 padded rows, 4-bit XOR swizzled
    if (x0 + 67 < 404) {
        const unsigned short* rowp = in + ((size_t)b * 404 + y0 + wave) * rowstride;
        #pragma unroll
        for (int it = 0; it < 17; ++it) {
            int xi = it * 4 + (lane >> 4);
            int srcc = (lane & 15) ^ (xi & 15);
            gll16(rowp + (size_t)(x0 + xi) * 128 + srcc * 8,
                  &As[(wave * 68 + it * 4) * 128]);
        }
    } else {
        for (int c = tid; c < 8 * 68 * 16; c += 512) {
            int r = c / (68 * 16);
            int rem = c % (68 * 16);
            int xi = rem >> 4, c16 = rem & 15;
            int xx = x0 + xi;
            short8v v = {};
            if (xx < 404)
                v = *reinterpret_cast<const short8v*>(
                    in + ((size_t)b * 404 + y0 + r) * rowstride + (size_t)xx * 128
                       + ((c16 ^ (xi & 15)) * 8));
            *reinterpret_cast<short8v*>((char*)As + (r * 68 + xi) * 256 + c16 * 16) = v;
        }
    }
    __syncthreads();

    // ---- pair-pipelined taps: Ba/Bb alternate, no runtime selection
    const unsigned short* wbase = wbuf + cog * 8192;
    short8v Ba[16], Bb[16];
    f32x4 acc[2][2][4] = {};
    loadW(Ba, wbase, llo, lhi);
    #pragma unroll
    for (int t = 0; t < 4; ++t) {
        loadW(Bb, wbase + (size_t)(2 * t + 1) * 16384, llo, lhi);
        tapCompute(Ba, acc, As, (2 * t) / 3, (2 * t) % 3, pxg, yg, llo, lhi);
        loadW(Ba, wbase + (size_t)(2 * t + 2) * 16384, llo, lhi);
        tapCompute(Bb, acc, As, (2 * t + 1) / 3, (2 * t + 1) % 3, pxg, yg, llo, lhi);
    }
    tapCompute(Ba, acc, As, 2, 2, pxg, yg, llo, lhi);

    if (NCHW_OUT) {
        // f32 NCHW: lane holds 4 consecutive px -> float4 stores
        #pragma unroll
        for (int j = 0; j < 4; ++j) {
            int co = cog * 64 + j * 16 + llo;
            float scale = rsqrtf(bv[co] + 1e-3f) * g[co];
            float shift = bsh[co] - bm[co] * scale;
            #pragma unroll
            for (int dy = 0; dy < 2; ++dy) {
                int y = y0 + yg * 2 + dy;
                #pragma unroll
                for (int i = 0; i < 2; ++i) {
                    int px = x0 + pxg * 32 + i * 16 + lhi * 4;
                    if (px < 400) {
                        float4 v;
                        v.x = fmaxf(acc[dy][i][j][0] * scale + shift, 0.f);
                        v.y = fmaxf(acc[dy][i][j][1] * scale + shift, 0.f);
                        v.z = fmaxf(acc[dy][i][j][2] * scale + shift, 0.f);
                        v.w = fmaxf(acc[dy][i][j][3] * scale + shift, 0.f);
                        *reinterpret_cast<float4*>(
                            (float*)out + (((size_t)b * 128 + co) * 400 + y) * 400 + px) = v;
                    }
                }
            }
        }
    } else {
        // bf16 NHWC: stage per-wave tile in LDS, then coalesced ushort8 stores
        __syncthreads();   // everyone done reading As
        unsigned short* Cw = As + wave * 4096;     // 8KB per wave
        #pragma unroll
        for (int j = 0; j < 4; ++j) {
            int co = cog * 64 + j * 16 + llo;
            float scale = rsqrtf(bv[co] + 1e-3f) * g[co];
            float shift = bsh[co] - bm[co] * scale;
            #pragma unroll
            for (int dy = 0; dy < 2; ++dy)
                #pragma unroll
                for (int i = 0; i < 2; ++i)
                    #pragma unroll
                    for (int rg = 0; rg < 4; ++rg)
                        Cw[dy * 2048 + (i * 16 + lhi * 4 + rg) * 64 + j * 16 + llo] =
                            f2bf(fmaxf(acc[dy][i][j][rg] * scale + shift, 0.f));
        }
        #pragma unroll
        for (int dy = 0; dy < 2; ++dy) {
            int y = y0 + yg * 2 + dy;
            #pragma unroll
            for (int s = 0; s < 4; ++s) {
                int pxl = s * 8 + (lane >> 3);
                int oct = lane & 7;
                int px = x0 + pxg * 32 + pxl;
                if (px < 400)
                    *reinterpret_cast<ushort8v*>(
                        (unsigned short*)out + (((size_t)b * 404 + y + 2) * 404 + px + 2) * 128
                                             + cog * 64 + oct * 8) =
                        *reinterpret_cast<const ushort8v*>(&Cw[dy * 2048 + pxl * 64 + oct * 8]);
            }
        }
    }
}

// ---------------------------------------------------------------- launcher
extern "C" void kernel_launch(void* const* d_in, const int* in_sizes, int n_in,
                              void* d_out, int out_size, void* d_ws, size_t ws_size,
                              hipStream_t stream) {
    const float* voxel_feat = (const float*)d_in[0];
    const int*   coors      = (const int*)d_in[1];
    const float* ciw0       = (const float*)d_in[2];
    const float* ciw1       = (const float*)d_in[3];
    const int* vx[2][2] = {{(const int*)d_in[4], (const int*)d_in[6]},
                           {(const int*)d_in[8], (const int*)d_in[10]}};
    const float* ipw = (const float*)d_in[12];
    const float* ipb = (const float*)d_in[13];
    const float* ow  = (const float*)d_in[14];
    const float* obp = (const float*)d_in[15];
    const float* l1w = (const float*)d_in[16];
    const float* l1b = (const float*)d_in[17];
    const float* l2w = (const float*)d_in[18];
    const float* l2b = (const float*)d_in[19];
    const float* g1  = (const float*)d_in[20];
    const float* b1  = (const float*)d_in[21];
    const float* g2  = (const float*)d_in[22];
    const float* b2  = (const float*)d_in[23];
    const float* cw  = (const float*)d_in[24];
    const float* bng = (const float*)d_in[25];
    const float* bnb = (const float*)d_in[26];
    const float* bnm = (const float*)d_in[27];
    const float* bnv = (const float*)d_in[28];

    float* F = (float*)d_ws;
    unsigned short* W0   = (unsigned short*)F;           // bf16 weights: 1,867,776
    unsigned short* ipwb = W0;                           // 589824
    unsigned short* owb  = W0 + 589824;                  // 196608
    unsigned short* l1wb = W0 + 786432;                  // 393216
    unsigned short* l2wb = W0 + 1179648;                 // 393216
    unsigned short* cwb  = W0 + 1572864;                 // 294912
    float* feat = F + 940000;                            // 7.68M f32
    unsigned short* featb = (unsigned short*)(F + 8620000);   // 7.68M bf16
    unsigned short* pos0  = (unsigned short*)(F + 12460000);  // 7.68M bf16
    unsigned short* pos1  = (unsigned short*)(F + 16300000);
    unsigned short* obufb = (unsigned short*)(F + 20140000);
    unsigned short* hbufb = (unsigned short*)(F + 23980000);  // 15.36M bf16
    // conv phase (pos/obuf/hbuf dead; feat still live for scatter):
    unsigned short* canvas1 = (unsigned short*)(F + 12460000);  // padded 41.78M bf16
    unsigned short* canvas2 = (unsigned short*)(F + 33360000);  // padded 41.78M bf16
    unsigned short* qkvb = (unsigned short*)d_out;       // 23.04M bf16 scratch

    feat_init<<<30000, 256, 0, stream>>>(voxel_feat, feat, featb);
    pos_kernel<<<30000, 256, 0, stream>>>(ciw0, pos0);
    pos_kernel<<<30000, 256, 0, stream>>>(ciw1, pos1);
    cvt_bf16<<<(589824 + 255) / 256, 256, 0, stream>>>(ipw, ipwb, 589824);
    cvt_bf16<<<(196608 + 255) / 256, 256, 0, stream>>>(ow,  owb,  196608);
    cvt_bf16<<<(393216 + 255) / 256, 256, 0, stream>>>(l1w, l1wb, 393216);
    cvt_bf16<<<(393216 + 255) / 256, 256, 0, stream>>>(l2w, l2wb, 393216);
    wtrans_kernel<<<(2 * 9 * 16384 + 255) / 256, 256, 0, stream>>>(cw, cwb);

    for (int li = 0; li < 12; ++li) {
        int s = li & 1;
        const unsigned short* pos = s ? pos1 : pos0;
        // QKV: q,k col-blocks get +pos (reg-staged); v block pure gll
        gemm_mfma<128, true, false, true, false><<<dim3(469, 3), 256, 0, stream>>>(
            featb, pos, 2, ipwb + (size_t)li * 49152, ipb + li * 384, qkvb, NVOX, 384,
            nullptr, nullptr, nullptr, nullptr);
        attn_kernel<25, 8><<<dim3(960, 1), 256, 0, stream>>>(qkvb, vx[s][0], 24000, obufb);
        attn_kernel<100, 2><<<dim3(360, 4), 256, 0, stream>>>(qkvb, vx[s][1], 36000, obufb);
        // out-proj + residual + LN1 fused
        gemm_mfma<128, false, false, false, true><<<dim3(469, 1), 256, 0, stream>>>(
            obufb, nullptr, 0, owb + (size_t)li * 16384, obp + li * 128, nullptr, NVOX, 128,
            feat, featb, g1 + li * 128, b1 + li * 128);
        // FFN1 + GELU, bf16 out
        gemm_mfma<128, false, true, true, false><<<dim3(469, 2), 256, 0, stream>>>(
            featb, nullptr, 0, l1wb + (size_t)li * 32768, l1b + li * 256, hbufb, NVOX, 256,
            nullptr, nullptr, nullptr, nullptr);
        // FFN2 + residual + LN2 fused
        gemm_mfma<256, false, false, false, true><<<dim3(469, 1), 256, 0, stream>>>(
            hbufb, nullptr, 0, l2wb + (size_t)li * 32768, l2b + li * 128, nullptr, NVOX, 128,
            feat, featb, g2 + li * 128, b2 + li * 128);
    }

    // BEV: zero canvas1 fully + canvas2 halo only, scatter, conv1, conv2
    hipMemsetAsync(canvas1, 0, (size_t)41783296 * 2, stream);
    halo_zero<<<(2 * 3216 * 16 + 255) / 256, 256, 0, stream>>>(canvas2);
    scatter_kernel<<<(NVOX * 16 + 255) / 256, 256, 0, stream>>>(feat, coors, canvas1);
    conv_mfma<false><<<dim3(7, 100, 2), 512, 0, stream>>>(
        canvas1, cwb, bng, bnb, bnm, bnv, canvas2);
    conv_mfma<true><<<dim3(7, 100, 2), 512, 0, stream>>>(
        canvas2, cwb + 9 * 16384, bng + 128, bnb + 128, bnm + 128, bnv + 128, (float*)d_out);
}

// Round 7
// 2493.595 us; speedup vs baseline: 1.4200x; 1.0979x over previous
//
#include <hip/hip_runtime.h>
#include <math.h>

#define NVOX 60000

typedef __attribute__((ext_vector_type(8))) short short8v;            // 8 bf16 raw
typedef __attribute__((ext_vector_type(8))) unsigned short ushort8v;  // 8 bf16 raw
typedef __attribute__((ext_vector_type(4))) float f32x4;

static __device__ __forceinline__ unsigned short f2bf(float f) {
    unsigned u = __float_as_uint(f);
    unsigned r = (u + 0x7fffu + ((u >> 16) & 1u)) >> 16;
    return (unsigned short)r;
}
static __device__ __forceinline__ float bf2f(unsigned short h) {
    return __uint_as_float(((unsigned)h) << 16);
}
// async global->LDS 16B per lane: dest = lds_base + lane*16 (wave-uniform base)
static __device__ __forceinline__ void gll16(const unsigned short* g, unsigned short* l) {
    __builtin_amdgcn_global_load_lds(
        (const __attribute__((address_space(1))) unsigned*)g,
        (__attribute__((address_space(3))) unsigned*)l,
        16, 0, 0);
}

// ---------------------------------------------------------------- pos embed (bf16 out)
__global__ __launch_bounds__(256) void pos_kernel(const float* __restrict__ ciw,
                                                  unsigned short* __restrict__ pos) {
    int idx = blockIdx.x * 256 + threadIdx.x;
    if (idx >= NVOX * 128) return;
    int n = idx >> 7, d = idx & 127;
    int c = d >> 6, t = (d & 63) >> 1;
    float xy = ciw[n * 2 + c] - 6.0f;
    float inv = exp2f((float)t * (13.287712379549449f / 32.0f)); // 10000^(t/32)
    float e = xy / inv;
    pos[idx] = f2bf((d & 1) ? cosf(e) : sinf(e));
}

// ------------------------------------------------------- fp32 -> bf16 convert
__global__ __launch_bounds__(256) void cvt_bf16(const float* __restrict__ in,
                                                unsigned short* __restrict__ out, int n) {
    int idx = blockIdx.x * 256 + threadIdx.x;
    if (idx < n) out[idx] = f2bf(in[idx]);
}

// -------------------------------------------- feat init: f32 copy + bf16 shadow
__global__ __launch_bounds__(256) void feat_init(const float* __restrict__ vf,
                                                 float* __restrict__ feat,
                                                 unsigned short* __restrict__ featb) {
    int idx = blockIdx.x * 256 + threadIdx.x;
    if (idx >= NVOX * 128) return;
    float v = vf[idx];
    feat[idx] = v;
    featb[idx] = f2bf(v);
}

// ----------------------------------------- MFMA GEMM: C = A*W^T + b (+variants)
template<int KTOT, bool ADD, bool GELU, bool CBF16, bool LNF>
__global__ __launch_bounds__(256) void gemm_mfma(
    const unsigned short* __restrict__ A, const unsigned short* __restrict__ Aadd, int add_nblk,
    const unsigned short* __restrict__ W, const float* __restrict__ bias,
    void* __restrict__ Cp, int M, int ldc,
    float* __restrict__ feat, unsigned short* __restrict__ featb,
    const float* __restrict__ lng, const float* __restrict__ lnb)
{
    __shared__ unsigned short smem[128 * 128];   // As(16KB) + Ws(16KB), reused as Cs(32KB)
    __shared__ float2 lnsum[128][2];
    unsigned short* As = smem;
    unsigned short* Ws = smem + 128 * 64;
    const int tid = threadIdx.x;
    const int lane = tid & 63, wave = tid >> 6;
    const int wr = wave >> 1, wc = wave & 1;
    const int llo = lane & 15, lhi = lane >> 4;
    const int m0 = blockIdx.x * 128;
    const int n0 = blockIdx.y * 128;
    const bool addp = ADD && ((int)blockIdx.y < add_nblk);
    const int gr = lane >> 3;           // row within 8-row group
    const int gc = (lane & 7) ^ gr;     // pre-swizzled source chunk
    f32x4 acc[4][4] = {};

    for (int k0 = 0; k0 < KTOT; k0 += 64) {
        #pragma unroll
        for (int p = 0; p < 4; ++p) {
            int r0 = wave * 32 + p * 8;
            gll16(W + (size_t)(n0 + r0 + gr) * KTOT + k0 + gc * 8, &Ws[r0 * 64]);
        }
        if (!addp) {
            #pragma unroll
            for (int p = 0; p < 4; ++p) {
                int r0 = wave * 32 + p * 8;
                gll16(A + (size_t)(m0 + r0 + gr) * KTOT + k0 + gc * 8, &As[r0 * 64]);
            }
        } else {
            #pragma unroll
            for (int p = 0; p < 4; ++p) {
                int c = tid + p * 256;
                int r = c >> 3, c16 = c & 7;
                int m = m0 + r;
                short8v av = {};
                if (m < M) {
                    ushort8v fa = *reinterpret_cast<const ushort8v*>(A + (size_t)m * KTOT + k0 + c16 * 8);
                    ushort8v pa = *reinterpret_cast<const ushort8v*>(Aadd + (size_t)m * 128 + k0 + c16 * 8);
                    #pragma unroll
                    for (int q = 0; q < 8; ++q) av[q] = (short)f2bf(bf2f(fa[q]) + bf2f(pa[q]));
                }
                *reinterpret_cast<short8v*>((char*)As + r * 128 + ((c16 * 16) ^ ((r & 7) << 4))) = av;
            }
        }
        __syncthreads();
        #pragma unroll
        for (int kk = 0; kk < 2; ++kk) {
            int kb = kk * 64 + lhi * 16;
            short8v af[4], bf[4];
            #pragma unroll
            for (int i = 0; i < 4; ++i) {
                int r = wr * 64 + i * 16 + llo;
                af[i] = *reinterpret_cast<const short8v*>((const char*)As + r * 128 + (kb ^ ((r & 7) << 4)));
                int cc = wc * 64 + i * 16 + llo;
                bf[i] = *reinterpret_cast<const short8v*>((const char*)Ws + cc * 128 + (kb ^ ((cc & 7) << 4)));
            }
            #pragma unroll
            for (int i = 0; i < 4; ++i)
                #pragma unroll
                for (int j = 0; j < 4; ++j)
                    acc[i][j] = __builtin_amdgcn_mfma_f32_16x16x32_bf16(af[i], bf[j], acc[i][j], 0, 0, 0);
        }
        __syncthreads();
    }

    if (LNF) {
        float s1[4][4] = {}, s2[4][4] = {};
        #pragma unroll
        for (int i = 0; i < 4; ++i)
            #pragma unroll
            for (int rg = 0; rg < 4; ++rg) {
                int m = m0 + wr * 64 + i * 16 + lhi * 4 + rg;
                if (m < M) {
                    #pragma unroll
                    for (int j = 0; j < 4; ++j) {
                        int n = wc * 64 + j * 16 + llo;
                        float x = feat[(size_t)m * 128 + n] + acc[i][j][rg] + bias[n];
                        acc[i][j][rg] = x;
                        s1[i][rg] += x; s2[i][rg] += x * x;
                    }
                }
            }
        #pragma unroll
        for (int i = 0; i < 4; ++i)
            #pragma unroll
            for (int rg = 0; rg < 4; ++rg) {
                #pragma unroll
                for (int off = 1; off < 16; off <<= 1) {
                    s1[i][rg] += __shfl_xor(s1[i][rg], off);
                    s2[i][rg] += __shfl_xor(s2[i][rg], off);
                }
                if (llo == 0)
                    lnsum[wr * 64 + i * 16 + lhi * 4 + rg][wc] = make_float2(s1[i][rg], s2[i][rg]);
            }
        __syncthreads();
        #pragma unroll
        for (int i = 0; i < 4; ++i)
            #pragma unroll
            for (int rg = 0; rg < 4; ++rg) {
                int r = wr * 64 + i * 16 + lhi * 4 + rg;
                int m = m0 + r;
                if (m >= M) continue;
                float2 a0 = lnsum[r][0], a1 = lnsum[r][1];
                float mu = (a0.x + a1.x) * 0.0078125f;
                float var = fmaxf((a0.y + a1.y) * 0.0078125f - mu * mu, 0.f);
                float inv = rsqrtf(var + 1e-5f);
                #pragma unroll
                for (int j = 0; j < 4; ++j) {
                    int n = wc * 64 + j * 16 + llo;
                    float v = (acc[i][j][rg] - mu) * inv * lng[n] + lnb[n];
                    feat[(size_t)m * 128 + n] = v;
                    featb[(size_t)m * 128 + n] = f2bf(v);
                }
            }
    } else if (CBF16) {
        #pragma unroll
        for (int j = 0; j < 4; ++j) {
            int nl = wc * 64 + j * 16 + llo;
            float bn = bias[n0 + nl];
            #pragma unroll
            for (int i = 0; i < 4; ++i)
                #pragma unroll
                for (int rg = 0; rg < 4; ++rg) {
                    float v = acc[i][j][rg] + bn;
                    if (GELU) v = 0.5f * v * (1.0f + erff(v * 0.7071067811865475f));
                    smem[(wr * 64 + i * 16 + lhi * 4 + rg) * 128 + nl] = f2bf(v);
                }
        }
        __syncthreads();
        unsigned short* C = (unsigned short*)Cp;
        #pragma unroll
        for (int c = 0; c < 8; ++c) {
            int idx = tid + c * 256;
            int r = idx >> 4, ch = idx & 15;
            if (m0 + r < M)
                *reinterpret_cast<ushort8v*>(C + (size_t)(m0 + r) * ldc + n0 + ch * 8) =
                    *reinterpret_cast<const ushort8v*>(&smem[r * 128 + ch * 8]);
        }
    } else {
        float* C = (float*)Cp;
        #pragma unroll
        for (int j = 0; j < 4; ++j) {
            int n = n0 + wc * 64 + j * 16 + llo;
            float bn = bias[n];
            #pragma unroll
            for (int i = 0; i < 4; ++i)
                #pragma unroll
                for (int rg = 0; rg < 4; ++rg) {
                    int m = m0 + wr * 64 + i * 16 + lhi * 4 + rg;
                    if (m < M) {
                        float v = acc[i][j][rg] + bn;
                        if (GELU) v = 0.5f * v * (1.0f + erff(v * 0.7071067811865475f));
                        C[(size_t)m * ldc + n] = v;
                    }
                }
        }
    }
}

// ------------------------------------------------------- windowed attention (bf16 qkv)
template<int CAPT, int HG>
__global__ __launch_bounds__(256) void attn_kernel(
    const unsigned short* __restrict__ qkv, const int* __restrict__ vlist, int nvox,
    unsigned short* __restrict__ oout)
{
    __shared__ float Ks[CAPT][HG * 16];
    __shared__ float Vs[CAPT][HG * 16];
    __shared__ int vl[CAPT];
    const int w = blockIdx.x;
    const int hb = blockIdx.y * HG;
    const int tid = threadIdx.x;
    const int T = min(CAPT, nvox - w * CAPT);
    if (tid < T) vl[tid] = vlist[w * CAPT + tid];
    constexpr int R8 = HG * 2;
    for (int idx = tid; idx < T * R8; idx += 256) {
        int t = idx / R8, c8 = (idx % R8) * 8;
        int vox = vlist[w * CAPT + t];
        const unsigned short* base = qkv + (size_t)vox * 384 + hb * 16 + c8;
        ushort8v kv = *reinterpret_cast<const ushort8v*>(base + 128);
        ushort8v vv = *reinterpret_cast<const ushort8v*>(base + 256);
        #pragma unroll
        for (int q = 0; q < 8; ++q) { Ks[t][c8 + q] = bf2f(kv[q]); Vs[t][c8 + q] = bf2f(vv[q]); }
    }
    __syncthreads();
    const int ITEMS = T * HG;
    for (int item = tid; item < ITEMS; item += 256) {
        int h = item & (HG - 1);
        int q = item / HG;
        int vq = vl[q];
        const unsigned short* qb = qkv + (size_t)vq * 384 + (hb + h) * 16;
        ushort8v qa = *reinterpret_cast<const ushort8v*>(qb);
        ushort8v qc = *reinterpret_cast<const ushort8v*>(qb + 8);
        float4 q0 = make_float4(bf2f(qa[0]), bf2f(qa[1]), bf2f(qa[2]), bf2f(qa[3]));
        float4 q1 = make_float4(bf2f(qa[4]), bf2f(qa[5]), bf2f(qa[6]), bf2f(qa[7]));
        float4 q2 = make_float4(bf2f(qc[0]), bf2f(qc[1]), bf2f(qc[2]), bf2f(qc[3]));
        float4 q3 = make_float4(bf2f(qc[4]), bf2f(qc[5]), bf2f(qc[6]), bf2f(qc[7]));
        float mx = -INFINITY, l = 0.f;
        float4 o0 = make_float4(0,0,0,0), o1 = o0, o2 = o0, o3 = o0;
        for (int t = 0; t < T; ++t) {
            const float4* kr = reinterpret_cast<const float4*>(&Ks[t][h * 16]);
            float4 k0 = kr[0], k1 = kr[1], k2 = kr[2], k3 = kr[3];
            float s = q0.x*k0.x + q0.y*k0.y + q0.z*k0.z + q0.w*k0.w
                    + q1.x*k1.x + q1.y*k1.y + q1.z*k1.z + q1.w*k1.w
                    + q2.x*k2.x + q2.y*k2.y + q2.z*k2.z + q2.w*k2.w
                    + q3.x*k3.x + q3.y*k3.y + q3.z*k3.z + q3.w*k3.w;
            s *= 0.25f;
            float mo = mx;
            mx = fmaxf(mx, s);
            float cc = __expf(mo - mx);
            float p  = __expf(s - mx);
            l = l * cc + p;
            const float4* vr = reinterpret_cast<const float4*>(&Vs[t][h * 16]);
            float4 v0 = vr[0], v1 = vr[1], v2 = vr[2], v3 = vr[3];
            o0.x = o0.x*cc + p*v0.x; o0.y = o0.y*cc + p*v0.y; o0.z = o0.z*cc + p*v0.z; o0.w = o0.w*cc + p*v0.w;
            o1.x = o1.x*cc + p*v1.x; o1.y = o1.y*cc + p*v1.y; o1.z = o1.z*cc + p*v1.z; o1.w = o1.w*cc + p*v1.w;
            o2.x = o2.x*cc + p*v2.x; o2.y = o2.y*cc + p*v2.y; o2.z = o2.z*cc + p*v2.z; o2.w = o2.w*cc + p*v2.w;
            o3.x = o3.x*cc + p*v3.x; o3.y = o3.y*cc + p*v3.y; o3.z = o3.z*cc + p*v3.z; o3.w = o3.w*cc + p*v3.w;
        }
        float rl = 1.0f / l;
        ushort8v r0, r1;
        r0[0]=f2bf(o0.x*rl); r0[1]=f2bf(o0.y*rl); r0[2]=f2bf(o0.z*rl); r0[3]=f2bf(o0.w*rl);
        r0[4]=f2bf(o1.x*rl); r0[5]=f2bf(o1.y*rl); r0[6]=f2bf(o1.z*rl); r0[7]=f2bf(o1.w*rl);
        r1[0]=f2bf(o2.x*rl); r1[1]=f2bf(o2.y*rl); r1[2]=f2bf(o2.z*rl); r1[3]=f2bf(o2.w*rl);
        r1[4]=f2bf(o3.x*rl); r1[5]=f2bf(o3.y*rl); r1[6]=f2bf(o3.z*rl); r1[7]=f2bf(o3.w*rl);
        unsigned short* op = oout + (size_t)vq * 128 + (hb + h) * 16;
        *reinterpret_cast<ushort8v*>(op) = r0;
        *reinterpret_cast<ushort8v*>(op + 8) = r1;
    }
}

// ------------------- BEV scatter into padded canvas (bf16, stride 420)
__global__ __launch_bounds__(256) void scatter_kernel(const float* __restrict__ feat,
    const int* __restrict__ coors, unsigned short* __restrict__ canvas)
{
    int idx = blockIdx.x * 256 + threadIdx.x;
    if (idx >= NVOX * 16) return;
    int n = idx >> 4, c8 = (idx & 15) << 3;
    int b = coors[n * 4], y = coors[n * 4 + 2], x = coors[n * 4 + 3];
    const float* src = feat + (size_t)n * 128 + c8;
    float4 u0 = *reinterpret_cast<const float4*>(src);
    float4 u1 = *reinterpret_cast<const float4*>(src + 4);
    ushort8v v;
    v[0]=f2bf(u0.x); v[1]=f2bf(u0.y); v[2]=f2bf(u0.z); v[3]=f2bf(u0.w);
    v[4]=f2bf(u1.x); v[5]=f2bf(u1.y); v[6]=f2bf(u1.z); v[7]=f2bf(u1.w);
    size_t p = (((size_t)b * 404 + y + 2) * 420 + x + 2) * 128 + c8;
    *reinterpret_cast<ushort8v*>(canvas + p) = v;
}

// ------------------- conv weight re-layout -> bf16 [i][ky*3+kx][cout][cin]
__global__ __launch_bounds__(256) void wtrans_kernel(const float* __restrict__ cw,
                                                     unsigned short* __restrict__ wbuf)
{
    int idx = blockIdx.x * 256 + threadIdx.x;
    if (idx >= 2 * 9 * 128 * 128) return;
    int ci = idx & 127;
    int co = (idx >> 7) & 127;
    int kk = (idx >> 14) % 9;
    int i  = idx / (9 * 16384);
    wbuf[idx] = f2bf(cw[(((size_t)i * 128 + co) * 128 + ci) * 9 + kk]);
}

// ---------------- 3x3 dilated(2) conv + BN + ReLU, LDS-A once + LDS-W double-buffered
// in: padded NHWC bf16 [2][404 rows][420 cols][128], fully zeroed beyond data.
// Block: 32px x 4y x 128co, 512 thr = 8 waves (2co x 4y). A: 8 rows x 36 px (73.7KB).
// W: per-tap 32KB, double-buffered, prefetched one tap ahead via global_load_lds.
template<bool NCHW_OUT>
__global__ __launch_bounds__(512, 1) void conv_mfma(
    const unsigned short* __restrict__ in, const unsigned short* __restrict__ wbuf,
    const float* __restrict__ g, const float* __restrict__ bsh,
    const float* __restrict__ bm, const float* __restrict__ bv,
    void* __restrict__ out)
{
    __shared__ unsigned short Ab[8 * 36 * 128];       // 73728 B
    __shared__ unsigned short Wb[2 * 128 * 128];      // 65536 B
    const int tid = threadIdx.x;
    const int lane = tid & 63, wave = tid >> 6;
    const int cog = wave & 1, yg = wave >> 1;
    const int llo = lane & 15, lhi = lane >> 4;
    const int x0 = blockIdx.x * 32, y0 = blockIdx.y * 4, b = blockIdx.z;
    const int c16s = lane & 15;

    // ---- stage A: canvas rows y0..y0+7, cols x0..x0+35, 4-bit XOR swizzle
    #pragma unroll
    for (int it = 0; it < 9; ++it) {
        int gidx = it * 32 + wave * 4 + lhi;          // 16B-chunk group id (0..287)
        int row = gidx / 36, xi = gidx % 36;
        gll16(in + (((size_t)b * 404 + y0 + row) * 420 + x0 + xi) * 128 + ((c16s ^ (xi & 15)) * 8),
              Ab + (size_t)(it * 512 + wave * 64) * 8);
    }
    // ---- stage W tap 0 into Wb[0]
    {
        const unsigned short* wt = wbuf;
        #pragma unroll
        for (int it = 0; it < 4; ++it) {
            int co = it * 32 + wave * 4 + lhi;
            gll16(wt + co * 128 + ((c16s ^ (co & 15)) * 8),
                  Wb + (size_t)(it * 512 + wave * 64) * 8);
        }
    }
    __syncthreads();

    f32x4 acc[2][4] = {};
    #pragma unroll
    for (int t = 0; t < 9; ++t) {
        if (t < 8) {   // prefetch next tap's weights into the other buffer
            const unsigned short* wt = wbuf + (size_t)(t + 1) * 16384;
            unsigned short* dst = Wb + ((t + 1) & 1) * 16384;
            #pragma unroll
            for (int it = 0; it < 4; ++it) {
                int co = it * 32 + wave * 4 + lhi;
                gll16(wt + co * 128 + ((c16s ^ (co & 15)) * 8),
                      dst + (size_t)(it * 512 + wave * 64) * 8);
            }
        }
        const unsigned short* Wp = Wb + (t & 1) * 16384;
        const int ky = t / 3, kx = t % 3;
        const int r = yg + 2 * ky;
        #pragma unroll
        for (int kk = 0; kk < 4; ++kk) {
            short8v a[2], w[4];
            #pragma unroll
            for (int i = 0; i < 2; ++i) {
                int xi = i * 16 + llo + 2 * kx;
                a[i] = *reinterpret_cast<const short8v*>(
                    (const char*)Ab + (r * 36 + xi) * 256 + ((kk * 64 + lhi * 16) ^ ((xi & 15) << 4)));
            }
            #pragma unroll
            for (int j = 0; j < 4; ++j) {
                int co = cog * 64 + j * 16 + llo;
                w[j] = *reinterpret_cast<const short8v*>(
                    (const char*)Wp + co * 256 + ((kk * 64 + lhi * 16) ^ ((co & 15) << 4)));
            }
            #pragma unroll
            for (int i = 0; i < 2; ++i)
                #pragma unroll
                for (int j = 0; j < 4; ++j)
                    acc[i][j] = __builtin_amdgcn_mfma_f32_16x16x32_bf16(a[i], w[j], acc[i][j], 0, 0, 0);
        }
        __syncthreads();
    }

    const int y = y0 + yg;
    if (NCHW_OUT) {
        // f32 NCHW: lane holds 4 consecutive px -> float4 stores
        #pragma unroll
        for (int j = 0; j < 4; ++j) {
            int co = cog * 64 + j * 16 + llo;
            float scale = rsqrtf(bv[co] + 1e-3f) * g[co];
            float shift = bsh[co] - bm[co] * scale;
            #pragma unroll
            for (int i = 0; i < 2; ++i) {
                int px = x0 + i * 16 + lhi * 4;
                if (px < 400) {
                    float4 v;
                    v.x = fmaxf(acc[i][j][0] * scale + shift, 0.f);
                    v.y = fmaxf(acc[i][j][1] * scale + shift, 0.f);
                    v.z = fmaxf(acc[i][j][2] * scale + shift, 0.f);
                    v.w = fmaxf(acc[i][j][3] * scale + shift, 0.f);
                    *reinterpret_cast<float4*>(
                        (float*)out + (((size_t)b * 128 + co) * 400 + y) * 400 + px) = v;
                }
            }
        }
    } else {
        // bf16 NHWC (padded stride 420): stage per-wave tile in Wb, coalesced 16B stores
        unsigned short* Cw = Wb + wave * 2048;
        #pragma unroll
        for (int j = 0; j < 4; ++j) {
            int co = cog * 64 + j * 16 + llo;
            float scale = rsqrtf(bv[co] + 1e-3f) * g[co];
            float shift = bsh[co] - bm[co] * scale;
            #pragma unroll
            for (int i = 0; i < 2; ++i)
                #pragma unroll
                for (int rg = 0; rg < 4; ++rg)
                    Cw[(i * 16 + lhi * 4 + rg) * 64 + j * 16 + llo] =
                        f2bf(fmaxf(acc[i][j][rg] * scale + shift, 0.f));
        }
        #pragma unroll
        for (int s = 0; s < 4; ++s) {
            int pxl = s * 8 + (lane >> 3);
            int oct = lane & 7;
            int px = x0 + pxl;
            if (px < 400)
                *reinterpret_cast<ushort8v*>(
                    (unsigned short*)out + (((size_t)b * 404 + y + 2) * 420 + px + 2) * 128
                                         + cog * 64 + oct * 8) =
                    *reinterpret_cast<const ushort8v*>(&Cw[pxl * 64 + oct * 8]);
        }
    }
}

// ---------------------------------------------------------------- launcher
extern "C" void kernel_launch(void* const* d_in, const int* in_sizes, int n_in,
                              void* d_out, int out_size, void* d_ws, size_t ws_size,
                              hipStream_t stream) {
    const float* voxel_feat = (const float*)d_in[0];
    const int*   coors      = (const int*)d_in[1];
    const float* ciw0       = (const float*)d_in[2];
    const float* ciw1       = (const float*)d_in[3];
    const int* vx[2][2] = {{(const int*)d_in[4], (const int*)d_in[6]},
                           {(const int*)d_in[8], (const int*)d_in[10]}};
    const float* ipw = (const float*)d_in[12];
    const float* ipb = (const float*)d_in[13];
    const float* ow  = (const float*)d_in[14];
    const float* obp = (const float*)d_in[15];
    const float* l1w = (const float*)d_in[16];
    const float* l1b = (const float*)d_in[17];
    const float* l2w = (const float*)d_in[18];
    const float* l2b = (const float*)d_in[19];
    const float* g1  = (const float*)d_in[20];
    const float* b1  = (const float*)d_in[21];
    const float* g2  = (const float*)d_in[22];
    const float* b2  = (const float*)d_in[23];
    const float* cw  = (const float*)d_in[24];
    const float* bng = (const float*)d_in[25];
    const float* bnb = (const float*)d_in[26];
    const float* bnm = (const float*)d_in[27];
    const float* bnv = (const float*)d_in[28];

    float* F = (float*)d_ws;
    unsigned short* W0   = (unsigned short*)F;           // bf16 weights: 1,867,776
    unsigned short* ipwb = W0;                           // 589824
    unsigned short* owb  = W0 + 589824;                  // 196608
    unsigned short* l1wb = W0 + 786432;                  // 393216
    unsigned short* l2wb = W0 + 1179648;                 // 393216
    unsigned short* cwb  = W0 + 1572864;                 // 294912
    float* feat = F + 940000;                            // 7.68M f32, ends at 8.62M
    unsigned short* featb = (unsigned short*)(F + 8620000);   // 7.68M bf16
    unsigned short* pos0  = (unsigned short*)(F + 12460000);  // 7.68M bf16
    unsigned short* pos1  = (unsigned short*)(F + 16300000);
    unsigned short* obufb = (unsigned short*)(F + 20140000);
    unsigned short* hbufb = (unsigned short*)(F + 23980000);  // 15.36M bf16
    // conv phase (featb/pos/obuf/hbuf dead; feat live for scatter):
    // padded canvases: [2][404][420][128] bf16 = 43,438,080 ushorts each
    unsigned short* canvas1 = (unsigned short*)(F + 8620000);   // ends F+30,339,040
    unsigned short* canvas2 = (unsigned short*)(F + 30339040);  // ends F+52,058,080
    unsigned short* qkvb = (unsigned short*)d_out;       // 23.04M bf16 scratch

    feat_init<<<30000, 256, 0, stream>>>(voxel_feat, feat, featb);
    pos_kernel<<<30000, 256, 0, stream>>>(ciw0, pos0);
    pos_kernel<<<30000, 256, 0, stream>>>(ciw1, pos1);
    cvt_bf16<<<(589824 + 255) / 256, 256, 0, stream>>>(ipw, ipwb, 589824);
    cvt_bf16<<<(196608 + 255) / 256, 256, 0, stream>>>(ow,  owb,  196608);
    cvt_bf16<<<(393216 + 255) / 256, 256, 0, stream>>>(l1w, l1wb, 393216);
    cvt_bf16<<<(393216 + 255) / 256, 256, 0, stream>>>(l2w, l2wb, 393216);
    wtrans_kernel<<<(2 * 9 * 16384 + 255) / 256, 256, 0, stream>>>(cw, cwb);

    for (int li = 0; li < 12; ++li) {
        int s = li & 1;
        const unsigned short* pos = s ? pos1 : pos0;
        gemm_mfma<128, true, false, true, false><<<dim3(469, 3), 256, 0, stream>>>(
            featb, pos, 2, ipwb + (size_t)li * 49152, ipb + li * 384, qkvb, NVOX, 384,
            nullptr, nullptr, nullptr, nullptr);
        attn_kernel<25, 8><<<dim3(960, 1), 256, 0, stream>>>(qkvb, vx[s][0], 24000, obufb);
        attn_kernel<100, 2><<<dim3(360, 4), 256, 0, stream>>>(qkvb, vx[s][1], 36000, obufb);
        gemm_mfma<128, false, false, false, true><<<dim3(469, 1), 256, 0, stream>>>(
            obufb, nullptr, 0, owb + (size_t)li * 16384, obp + li * 128, nullptr, NVOX, 128,
            feat, featb, g1 + li * 128, b1 + li * 128);
        gemm_mfma<128, false, true, true, false><<<dim3(469, 2), 256, 0, stream>>>(
            featb, nullptr, 0, l1wb + (size_t)li * 32768, l1b + li * 256, hbufb, NVOX, 256,
            nullptr, nullptr, nullptr, nullptr);
        gemm_mfma<256, false, false, false, true><<<dim3(469, 1), 256, 0, stream>>>(
            hbufb, nullptr, 0, l2wb + (size_t)li * 32768, l2b + li * 128, nullptr, NVOX, 128,
            feat, featb, g2 + li * 128, b2 + li * 128);
    }

    // BEV: zero both padded canvases (contiguous), scatter, conv1, conv2
    hipMemsetAsync(canvas1, 0, (size_t)43438080 * 2 * 2, stream);
    scatter_kernel<<<(NVOX * 16 + 255) / 256, 256, 0, stream>>>(feat, coors, canvas1);
    conv_mfma<false><<<dim3(13, 100, 2), 512, 0, stream>>>(
        canvas1, cwb, bng, bnb, bnm, bnv, canvas2);
    conv_mfma<true><<<dim3(13, 100, 2), 512, 0, stream>>>(
        canvas2, cwb + 9 * 16384, bng + 128, bnb + 128, bnm + 128, bnv + 128, (float*)d_out);
}